// Round 5
// baseline (1922.828 us; speedup 1.0000x reference)
//
#include <hip/hip_runtime.h>
#include <cstdint>
#include <cstddef>

#define NG 512        // NUM_GRAPHS
#define NN 131072     // N_NODES
#define NE 4194304    // N_EDGES
#define FIN 54        // F_IN
#define HG 16         // H_GCN
#define HL 32         // H_LSTM
#define NC 192        // N_CLASSES
#define TS 1024       // MAX_SEQ_LEN

typedef float fvec16 __attribute__((ext_vector_type(16)));

__device__ __forceinline__ float rcpf(float x){ return __builtin_amdgcn_rcpf(x); }
__device__ __forceinline__ float sigf(float x){ return rcpf(1.0f + __expf(-x)); }
__device__ __forceinline__ float tanhfast(float x){ return 1.0f - 2.0f*rcpf(__expf(2.0f*x) + 1.0f); }

// Pin a pointer as wave-uniform (SGPR) so loads through it become s_load_*.
__device__ __forceinline__ const fvec16* uni16(const float* p){
  unsigned long long v = (unsigned long long)p;
  unsigned lo = __builtin_amdgcn_readfirstlane((unsigned)v);
  unsigned hi = __builtin_amdgcn_readfirstlane((unsigned)(v >> 32));
  return (const fvec16*)((((unsigned long long)hi) << 32) | lo);
}

// ---------------- init: ecnt=0, counts=0 ----------------
__global__ void k_init0(int* __restrict__ ecnt, int* __restrict__ counts){
  int i = blockIdx.x*256 + threadIdx.x;
  if (i < NN) ecnt[i] = 0;
  if (i < NG) counts[i] = 0;
}

// ---------------- in-degree histogram + per-graph node counts ----------------
__global__ void k_count(const int* __restrict__ ei, const int* __restrict__ batch,
                        int* __restrict__ ecnt, int* __restrict__ counts){
  int i = blockIdx.x*256 + threadIdx.x;
  if (i < NE) atomicAdd(&ecnt[ei[NE + i]], 1);
  if (i < NN) atomicAdd(&counts[batch[i]], 1);
}

// ---------------- per-256-chunk sums of ecnt ----------------
__global__ void k_bsum(const int* __restrict__ ecnt, int* __restrict__ bsum){
  __shared__ int s[256];
  int t = threadIdx.x;
  s[t] = ecnt[blockIdx.x*256 + t];
  __syncthreads();
  for (int o = 128; o > 0; o >>= 1){ if (t < o) s[t] += s[t+o]; __syncthreads(); }
  if (t == 0) bsum[blockIdx.x] = s[0];
}

// ---------------- dual exclusive scan of two 512-arrays (1 block, 512 thr) ----------------
__global__ void k_scan2(const int* __restrict__ a, int* __restrict__ ax,
                        const int* __restrict__ b, int* __restrict__ bx){
  __shared__ int s[NG];
  int t = threadIdx.x;
  s[t] = a[t]; __syncthreads();
  for (int o = 1; o < NG; o <<= 1){ int v = (t >= o) ? s[t-o] : 0; __syncthreads(); s[t] += v; __syncthreads(); }
  ax[t] = s[t] - a[t];
  __syncthreads();
  s[t] = b[t]; __syncthreads();
  for (int o = 1; o < NG; o <<= 1){ int v = (t >= o) ? s[t-o] : 0; __syncthreads(); s[t] += v; __syncthreads(); }
  bx[t] = s[t] - b[t];
}

// ---------------- per-node edge offsets (block-local scan + chunk base) ----------------
__global__ void k_eoff(const int* __restrict__ ecnt, const int* __restrict__ bstart,
                       int* __restrict__ eoff, int* __restrict__ cursor){
  __shared__ int s[256];
  int t = threadIdx.x, i = blockIdx.x*256 + t;
  int v = ecnt[i];
  s[t] = v; __syncthreads();
  for (int o = 1; o < 256; o <<= 1){ int u = (t >= o) ? s[t-o] : 0; __syncthreads(); s[t] += u; __syncthreads(); }
  int ex = s[t] - v + bstart[blockIdx.x];
  eoff[i] = ex; cursor[i] = ex;
}

__global__ void k_dinv(const int* __restrict__ ecnt, float* __restrict__ dinv){
  int i = blockIdx.x*256 + threadIdx.x;
  if (i < NN) dinv[i] = 1.0f / sqrtf((float)(ecnt[i] + 1));  // deg = indeg + self-loop >= 1
}

// ---------------- CSR placement: csr[eoff[dst]..] = src ----------------
__global__ void k_place(const int* __restrict__ ei, int* __restrict__ cursor, int* __restrict__ csr){
  int e = blockIdx.x*256 + threadIdx.x;
  if (e >= NE) return;
  int d = ei[NE + e];
  int pos = atomicAdd(&cursor[d], 1);
  csr[pos] = ei[e];
}

// ---------------- xa = x @ w1  (no bias yet) ----------------
__global__ void k_lin1(const float* __restrict__ x, const float* __restrict__ w1,
                       float* __restrict__ xa){
  __shared__ float w[FIN*HG];
  int tid = threadIdx.x;
  for (int i = tid; i < FIN*HG; i += 256) w[i] = w1[i];
  __syncthreads();
  int id = blockIdx.x*256 + tid;
  if (id >= NN*HG) return;
  int node = id >> 4, f = id & 15;
  const float* xr = x + (size_t)node*FIN;
  float acc = 0.0f;
#pragma unroll
  for (int k = 0; k < FIN; k++) acc = fmaf(xr[k], w[k*HG + f], acc);
  xa[id] = acc;
}

// ---------------- gather conv: out[d] = (sum_{s in N(d)} v[s]*dinv[s] + v[d]*dinv[d]) * dinv[d] ----------------
// 16 lanes per dst node (one per feature). No atomics.
__global__ void k_gather(const float* __restrict__ v, const int* __restrict__ csr,
                         const int* __restrict__ eoff, const int* __restrict__ ecnt,
                         const float* __restrict__ dinv, const float* __restrict__ bias,
                         int dorelu, float* __restrict__ out){
  int gid = blockIdx.x*16 + (threadIdx.x >> 4);
  int f = threadIdx.x & 15;
  float dv = dinv[gid];
  float a0 = v[(size_t)gid*HG + f] * dv, a1 = 0.0f, a2 = 0.0f, a3 = 0.0f;
  int o = eoff[gid], n = ecnt[gid];
  int i = 0;
  for (; i + 4 <= n; i += 4){
    int s0 = csr[o+i], s1 = csr[o+i+1], s2 = csr[o+i+2], s3 = csr[o+i+3];
    a0 = fmaf(v[(size_t)s0*HG + f], dinv[s0], a0);
    a1 = fmaf(v[(size_t)s1*HG + f], dinv[s1], a1);
    a2 = fmaf(v[(size_t)s2*HG + f], dinv[s2], a2);
    a3 = fmaf(v[(size_t)s3*HG + f], dinv[s3], a3);
  }
  for (; i < n; i++){
    int s = csr[o+i];
    a0 = fmaf(v[(size_t)s*HG + f], dinv[s], a0);
  }
  float acc = ((a0 + a1) + (a2 + a3)) * dv;
  if (dorelu) acc = fmaxf(acc + bias[f], 0.0f);
  out[(size_t)gid*HG + f] = acc;
}

// ---------------- hb = relu(agg + b1) @ w2 ----------------
__global__ void k_relu_lin(const float* __restrict__ agg, const float* __restrict__ b1,
                           const float* __restrict__ w2, float* __restrict__ hb){
  __shared__ float w[HG*HG];
  __shared__ float bb[HG];
  int tid = threadIdx.x;
  if (tid < HG*HG) w[tid] = w2[tid];
  if (tid < HG) bb[tid] = b1[tid];
  __syncthreads();
  int id = blockIdx.x*256 + tid;
  if (id >= NN*HG) return;
  int node = id >> 4, f = id & 15;
  const float* ar = agg + (size_t)node*HG;
  float acc = 0.0f;
#pragma unroll
  for (int k = 0; k < HG; k++){
    float h = fmaxf(ar[k] + bb[k], 0.0f);
    acc = fmaf(h, w[k*HG + f], acc);
  }
  hb[id] = acc;
}

// ============ BiLSTM: 2 waves per (graph,dir), one gate row per lane ============
// wave0: i (lanes 0-31), g (lanes 32-63); wave1: f (lanes 0-31, owns c),
// o (lanes 32-63, owns h). x via wave-uniform s_load (SGPR operands, no LDS);
// h via LDS b128 broadcast; weights pinned in VGPRs via opaque asm.

// ---------------- layer 0 ----------------
__global__ __launch_bounds__(128, 2) void k_lstm0(
    const float* __restrict__ h2in, const int* __restrict__ starts, const int* __restrict__ counts,
    const float* __restrict__ wih, const float* __restrict__ whh,
    const float* __restrict__ bih, const float* __restrict__ bhh,
    float* __restrict__ out0, int* __restrict__ tconv)
{
  const int g = blockIdx.x >> 1, dir = blockIdx.x & 1;
  const int tid = threadIdx.x;
  const int wv = tid >> 6, lane = tid & 63;
  const int sub = lane & 31, hi = lane >> 5;
  const int r = wv ? (hi ? 96 + sub : 32 + sub) : (hi ? 64 + sub : sub);
  float wr[HG], ur[HL];
  { const float* wp = wih + (size_t)dir*128*HG + (size_t)r*HG;
    const float* up = whh + (size_t)dir*128*HL + (size_t)r*HL;
#pragma unroll
    for (int k = 0; k < HG; k++) wr[k] = wp[k];
#pragma unroll
    for (int k = 0; k < HL; k++) ur[k] = up[k];
  }
#pragma unroll
  for (int k = 0; k < HG; k++) asm volatile("" : "+v"(wr[k]));
#pragma unroll
  for (int k = 0; k < HL; k++) asm volatile("" : "+v"(ur[k]));
  const float pb = bih[dir*128 + r] + bhh[dir*128 + r];
  int cnt = counts[g]; if (cnt > TS) cnt = TS;
  const int s0 = starts[g];
  float* outg = out0 + (size_t)g*TS*64 + dir*32;

  __shared__ __align__(16) float hbuf[2][HL];
  __shared__ __align__(16) float pbuf[HL];
  __shared__ int flagbuf[2];
  __shared__ unsigned long long azm[2];

  unsigned long long bz = __ballot(pb == 0.0f);
  if (lane == 0) azm[wv] = bz;
  if (tid < HL) hbuf[0][tid] = 0.0f;
  if (tid < 2) flagbuf[tid] = 0;
  __syncthreads();
  bool allzero = (azm[0] == ~0ull) && (azm[1] == ~0ull);

  int t0, dt;
  bool skipall = false;
  if (dir == 0){ t0 = 0; dt = 1; }
  else {
    if (allzero){
      // zero bias + zero input keeps state exactly 0 -> rows >= cnt are 0
      for (int rr = cnt + (tid >> 5); rr < TS; rr += 4) outg[(size_t)rr*64 + sub] = 0.0f;
      t0 = cnt - 1; dt = -1;
      if (t0 < 0) skipall = true;
    } else { t0 = TS - 1; dt = -1; }
  }

  int t = t0, cur = 0;
  float c = 0.0f, h = 0.0f;
  bool convdone = false;

  if (!skipall)
  for (;;){
    int nxt = cur ^ 1;
    float a0 = pb, a1 = 0.0f, a2 = 0.0f, a3 = 0.0f;
    bool hasx = (t < cnt);
    fvec16 xv;
    if (hasx) xv = *uni16(h2in + (size_t)(s0 + t)*HG);   // s_load, covered by h-FMAs
    const float4* h4 = (const float4*)hbuf[cur];
#pragma unroll
    for (int q = 0; q < HL/4; q++){ float4 hv = h4[q];
      a0 = fmaf(hv.x, ur[4*q+0], a0); a1 = fmaf(hv.y, ur[4*q+1], a1);
      a2 = fmaf(hv.z, ur[4*q+2], a2); a3 = fmaf(hv.w, ur[4*q+3], a3); }
    if (hasx){
#pragma unroll
      for (int k = 0; k < 4; k++){
        a0 = fmaf(xv[4*k+0], wr[4*k+0], a0);
        a1 = fmaf(xv[4*k+1], wr[4*k+1], a1);
        a2 = fmaf(xv[4*k+2], wr[4*k+2], a2);
        a3 = fmaf(xv[4*k+3], wr[4*k+3], a3);
      }
    }
    float a = (a0 + a1) + (a2 + a3);
    float sv1 = 0.0f;
    if (wv == 0){
      float u  = hi ? (a + a) : a;
      float sv = sigf(u);
      float v  = hi ? (sv + sv - 1.0f) : sv;   // hi: tanh(g); lo: sig(i)
      float gv = __shfl(v, 32 + sub);
      float p  = v * gv;                        // valid on lo lanes
      if (lane < HL) pbuf[lane] = p;
    } else {
      sv1 = sigf(a);                            // f or o
    }
    __syncthreads();  // barrier1: pbuf visible
    if (wv == 1){
      float cn = 0.0f, tcn = 0.0f;
      if (!hi){ cn = fmaf(sv1, c, pbuf[sub]); tcn = tanhfast(cn); }
      float tcs = __shfl(tcn, sub);
      bool eq;
      if (!hi){ eq = (cn == c); c = cn; }
      else {
        float hn = sv1 * tcs;
        eq = (hn == h); h = hn;
        hbuf[nxt][sub] = h;
        outg[(size_t)t*64 + sub] = h;
      }
      unsigned long long m = __ballot(eq);
      bool conv = (m == ~0ull) && (dir == 0) && (t >= cnt + 1);
      if (lane == 32) flagbuf[nxt] = conv ? 1 : 0;
    }
    __syncthreads();  // barrier2: hbuf[nxt], flag visible
    if (flagbuf[nxt]){
      // state fixed under constant (zero) input: all remaining rows equal h*
      float hval = hbuf[nxt][sub];
      for (int rr = t + 1 + (tid >> 5); rr < TS; rr += 4) outg[(size_t)rr*64 + sub] = hval;
      if (tid == 96) tconv[g] = t - 1;   // rows t-1.. are bitwise constant
      convdone = true;
      break;
    }
    t += dt;
    if (dir == 0){ if (t >= TS) break; } else { if (t < 0) break; }
    cur = nxt;
  }
  if (dir == 0 && !convdone && tid == 96) tconv[g] = TS;
}

// ---------------- layer 1 + mean pool ----------------
__global__ __launch_bounds__(128, 2) void k_lstm1(
    const float* __restrict__ gl0, const int* __restrict__ tconv,
    const float* __restrict__ wih, const float* __restrict__ whh,
    const float* __restrict__ bih, const float* __restrict__ bhh,
    float* __restrict__ pooled)
{
  const int g = blockIdx.x >> 1, dir = blockIdx.x & 1;
  const int tid = threadIdx.x;
  const int wv = tid >> 6, lane = tid & 63;
  const int sub = lane & 31, hi = lane >> 5;
  const int r = wv ? (hi ? 96 + sub : 32 + sub) : (hi ? 64 + sub : sub);
  float wr[64], ur[HL];
  { const float* wp = wih + (size_t)dir*128*64 + (size_t)r*64;
    const float* up = whh + (size_t)dir*128*HL + (size_t)r*HL;
#pragma unroll
    for (int k = 0; k < 64; k++) wr[k] = wp[k];
#pragma unroll
    for (int k = 0; k < HL; k++) ur[k] = up[k];
  }
#pragma unroll
  for (int k = 0; k < 64; k++) asm volatile("" : "+v"(wr[k]));
#pragma unroll
  for (int k = 0; k < HL; k++) asm volatile("" : "+v"(ur[k]));
  const float pb = bih[dir*128 + r] + bhh[dir*128 + r];
  const float* gin = gl0 + (size_t)g*TS*64;
  const int tcv = tconv[g];

  __shared__ __align__(16) float hbuf[2][HL];
  __shared__ __align__(16) float pbuf[HL];
  __shared__ int flagbuf[2];

  if (tid < HL) hbuf[0][tid] = 0.0f;
  if (tid < 2) flagbuf[tid] = 0;
  __syncthreads();

  const int t0 = dir ? (TS - 1) : 0, dt = dir ? -1 : 1;
  int t = t0, cur = 0;
  float c = 0.0f, h = 0.0f, hsum = 0.0f;

  for (;;){
    int nxt = cur ^ 1;
    const fvec16* xr = uni16(gin + (size_t)t*64);       // s_load x4, covered by h-FMAs
    fvec16 x0 = xr[0], x1 = xr[1], x2 = xr[2], x3 = xr[3];
    float a0 = pb, a1 = 0.0f, a2 = 0.0f, a3 = 0.0f;
    const float4* h4 = (const float4*)hbuf[cur];
#pragma unroll
    for (int q = 0; q < HL/4; q++){ float4 hv = h4[q];
      a0 = fmaf(hv.x, ur[4*q+0], a0); a1 = fmaf(hv.y, ur[4*q+1], a1);
      a2 = fmaf(hv.z, ur[4*q+2], a2); a3 = fmaf(hv.w, ur[4*q+3], a3); }
#pragma unroll
    for (int k = 0; k < 16; k++){
      a0 = fmaf(x0[k], wr[k],      a0);
      a1 = fmaf(x1[k], wr[16 + k], a1);
      a2 = fmaf(x2[k], wr[32 + k], a2);
      a3 = fmaf(x3[k], wr[48 + k], a3);
    }
    float a = (a0 + a1) + (a2 + a3);
    float sv1 = 0.0f;
    if (wv == 0){
      float u  = hi ? (a + a) : a;
      float sv = sigf(u);
      float v  = hi ? (sv + sv - 1.0f) : sv;
      float gv = __shfl(v, 32 + sub);
      float p  = v * gv;
      if (lane < HL) pbuf[lane] = p;
    } else {
      sv1 = sigf(a);
    }
    __syncthreads();  // barrier1
    if (wv == 1){
      float cn = 0.0f, tcn = 0.0f;
      if (!hi){ cn = fmaf(sv1, c, pbuf[sub]); tcn = tanhfast(cn); }
      float tcs = __shfl(tcn, sub);
      bool eq;
      if (!hi){ eq = (cn == c); c = cn; }
      else {
        float hn = sv1 * tcs;
        eq = (hn == h); h = hn;
        hsum += h;
        hbuf[nxt][sub] = h;
      }
      unsigned long long m = __ballot(eq);
      bool conv = (m == ~0ull) && (t >= tcv + 1);
      if (lane == 32) flagbuf[nxt] = conv ? 1 : 0;
    }
    __syncthreads();  // barrier2
    if (flagbuf[nxt]){
      if (dir == 0){
        // x constant for all remaining t; state fixed -> close the mean
        if (wv == 1 && hi) hsum += h * (float)(TS - 1 - t);
        break;
      } else {
        // rows [tcv, t-1] all equal current x; state fixed -> h* repeats
        if (wv == 1 && hi) hsum += h * (float)(t - tcv);
        t = tcv - 1;
        if (t < 0) break;
        cur = nxt;
        continue;
      }
    }
    t += dt;
    if (dir == 0){ if (t >= TS) break; } else { if (t < 0) break; }
    cur = nxt;
  }
  if (wv == 1 && hi) pooled[(size_t)g*64 + dir*32 + sub] = hsum * (1.0f/(float)TS);
}

// ---------------- FC: out = pooled @ fc_w + fc_b ----------------
__global__ void k_fc(const float* __restrict__ pooled, const float* __restrict__ fcw,
                     const float* __restrict__ fcb, float* __restrict__ out){
  __shared__ float p[64];
  int g = blockIdx.x, cix = threadIdx.x;
  if (cix < 64) p[cix] = pooled[(size_t)g*64 + cix];
  __syncthreads();
  float acc = fcb[cix];
#pragma unroll
  for (int k = 0; k < 64; k++) acc = fmaf(p[k], fcw[k*NC + cix], acc);
  out[(size_t)g*NC + cix] = acc;
}

extern "C" void kernel_launch(void* const* d_in, const int* in_sizes, int n_in,
                              void* d_out, int out_size, void* d_ws, size_t ws_size,
                              hipStream_t stream) {
  const float* x        = (const float*)d_in[0];
  const int*   ei       = (const int*)  d_in[1];
  const int*   batch    = (const int*)  d_in[2];
  const float* gcn_w1   = (const float*)d_in[3];
  const float* gcn_b1   = (const float*)d_in[4];
  const float* gcn_w2   = (const float*)d_in[5];
  const float* gcn_b2   = (const float*)d_in[6];
  const float* l0_wih   = (const float*)d_in[7];
  const float* l0_whh   = (const float*)d_in[8];
  const float* l0_bih   = (const float*)d_in[9];
  const float* l0_bhh   = (const float*)d_in[10];
  const float* l1_wih   = (const float*)d_in[11];
  const float* l1_whh   = (const float*)d_in[12];
  const float* l1_bih   = (const float*)d_in[13];
  const float* l1_bhh   = (const float*)d_in[14];
  const float* fc_w     = (const float*)d_in[15];
  const float* fc_b     = (const float*)d_in[16];
  float* out = (float*)d_out;

  // workspace layout (4B units; every region 256B-aligned)
  float* ws   = (float*)d_ws;
  float* B0   = ws;                        // NN*16
  float* B1   = B0 + (size_t)NN*HG;        // NN*16
  float* B2   = B1 + (size_t)NN*HG;        // NN*16
  float* dinv = B2 + (size_t)NN*HG;        // NN
  int*   ecnt   = (int*)(dinv + NN);       // NN
  int*   eoff   = ecnt + NN;               // NN
  int*   cursor = eoff + NN;               // NN
  int*   counts = cursor + NN;             // 512
  int*   starts = counts + NG;             // 512
  int*   tconv  = starts + NG;             // 512
  int*   bsum   = tconv + NG;              // 512
  int*   bstart = bsum + NG;               // 512
  float* pooled = (float*)(bstart + NG);   // 512*64
  int*   csr    = (int*)(pooled + (size_t)NG*64);  // NE
  float* out0   = (float*)(csr + (size_t)NE);      // 512*1024*64
  size_t needed = ((size_t)((float*)out0 - ws) + (size_t)NG*TS*64) * sizeof(float);
  if (ws_size < needed) return;  // fail loudly (poisoned d_out) rather than corrupt

  k_init0 <<<(NN+255)/256, 256, 0, stream>>>(ecnt, counts);
  k_count <<<(NE+255)/256, 256, 0, stream>>>(ei, batch, ecnt, counts);
  k_bsum  <<<NN/256, 256, 0, stream>>>(ecnt, bsum);
  k_scan2 <<<1, NG, 0, stream>>>(counts, starts, bsum, bstart);
  k_eoff  <<<NN/256, 256, 0, stream>>>(ecnt, bstart, eoff, cursor);
  k_dinv  <<<(NN+255)/256, 256, 0, stream>>>(ecnt, dinv);
  k_place <<<(NE+255)/256, 256, 0, stream>>>(ei, cursor, csr);
  k_lin1  <<<(NN*HG)/256, 256, 0, stream>>>(x, gcn_w1, B0);
  k_gather<<<(NN*HG)/256, 256, 0, stream>>>(B0, csr, eoff, ecnt, dinv, gcn_b2, 0, B1);
  k_relu_lin<<<(NN*HG)/256, 256, 0, stream>>>(B1, gcn_b1, gcn_w2, B2);
  k_gather<<<(NN*HG)/256, 256, 0, stream>>>(B2, csr, eoff, ecnt, dinv, gcn_b2, 1, B1);
  k_lstm0 <<<NG*2, 128, 0, stream>>>(B1, starts, counts, l0_wih, l0_whh, l0_bih, l0_bhh, out0, tconv);
  k_lstm1 <<<NG*2, 128, 0, stream>>>(out0, tconv, l1_wih, l1_whh, l1_bih, l1_bhh, pooled);
  k_fc    <<<NG, NC, 0, stream>>>(pooled, fc_w, fc_b, out);
}

// Round 6
// 1759.853 us; speedup vs baseline: 1.0926x; 1.0926x over previous
//
#include <hip/hip_runtime.h>
#include <cstdint>
#include <cstddef>

#define NG 512        // NUM_GRAPHS
#define NN 131072     // N_NODES
#define NE 4194304    // N_EDGES
#define FIN 54        // F_IN
#define HG 16         // H_GCN
#define HL 32         // H_LSTM
#define NC 192        // N_CLASSES
#define TS 1024       // MAX_SEQ_LEN

__device__ __forceinline__ float rcpf(float x){ return __builtin_amdgcn_rcpf(x); }
__device__ __forceinline__ float sigf(float x){ return rcpf(1.0f + __expf(-x)); }
__device__ __forceinline__ float tanhfast(float x){ return 1.0f - 2.0f*rcpf(__expf(2.0f*x) + 1.0f); }

// Wave-uniform row load kept in the VECTOR (vmcnt) domain: force the address
// into VGPRs so the compiler cannot scalarize to s_load (R5 lesson: SMEM and
// DS share lgkmcnt out-of-order -> serializing waits). Same-address lanes
// coalesce to one cacheline fetch + broadcast.
__device__ __forceinline__ float4 uload4(const float* p){
  unsigned long long a = (unsigned long long)p;
  asm volatile("" : "+v"(a));
  return *(const float4*)a;
}

// ---------------- init: ecnt=0, counts=0 ----------------
__global__ void k_init0(int* __restrict__ ecnt, int* __restrict__ counts){
  int i = blockIdx.x*256 + threadIdx.x;
  if (i < NN) ecnt[i] = 0;
  if (i < NG) counts[i] = 0;
}

// ---------------- in-degree histogram + per-graph node counts ----------------
__global__ void k_count(const int* __restrict__ ei, const int* __restrict__ batch,
                        int* __restrict__ ecnt, int* __restrict__ counts){
  int i = blockIdx.x*256 + threadIdx.x;
  if (i < NE) atomicAdd(&ecnt[ei[NE + i]], 1);
  if (i < NN) atomicAdd(&counts[batch[i]], 1);
}

// ---------------- per-256-chunk sums of ecnt ----------------
__global__ void k_bsum(const int* __restrict__ ecnt, int* __restrict__ bsum){
  __shared__ int s[256];
  int t = threadIdx.x;
  s[t] = ecnt[blockIdx.x*256 + t];
  __syncthreads();
  for (int o = 128; o > 0; o >>= 1){ if (t < o) s[t] += s[t+o]; __syncthreads(); }
  if (t == 0) bsum[blockIdx.x] = s[0];
}

// ---------------- dual exclusive scan of two 512-arrays (1 block, 512 thr) ----------------
__global__ void k_scan2(const int* __restrict__ a, int* __restrict__ ax,
                        const int* __restrict__ b, int* __restrict__ bx){
  __shared__ int s[NG];
  int t = threadIdx.x;
  s[t] = a[t]; __syncthreads();
  for (int o = 1; o < NG; o <<= 1){ int v = (t >= o) ? s[t-o] : 0; __syncthreads(); s[t] += v; __syncthreads(); }
  ax[t] = s[t] - a[t];
  __syncthreads();
  s[t] = b[t]; __syncthreads();
  for (int o = 1; o < NG; o <<= 1){ int v = (t >= o) ? s[t-o] : 0; __syncthreads(); s[t] += v; __syncthreads(); }
  bx[t] = s[t] - b[t];
}

// ---------------- per-node edge offsets (block-local scan + chunk base) ----------------
__global__ void k_eoff(const int* __restrict__ ecnt, const int* __restrict__ bstart,
                       int* __restrict__ eoff, int* __restrict__ cursor){
  __shared__ int s[256];
  int t = threadIdx.x, i = blockIdx.x*256 + t;
  int v = ecnt[i];
  s[t] = v; __syncthreads();
  for (int o = 1; o < 256; o <<= 1){ int u = (t >= o) ? s[t-o] : 0; __syncthreads(); s[t] += u; __syncthreads(); }
  int ex = s[t] - v + bstart[blockIdx.x];
  eoff[i] = ex; cursor[i] = ex;
}

__global__ void k_dinv(const int* __restrict__ ecnt, float* __restrict__ dinv){
  int i = blockIdx.x*256 + threadIdx.x;
  if (i < NN) dinv[i] = 1.0f / sqrtf((float)(ecnt[i] + 1));  // deg = indeg + self-loop >= 1
}

// ---------------- CSR placement: csr[eoff[dst]..] = src ----------------
__global__ void k_place(const int* __restrict__ ei, int* __restrict__ cursor, int* __restrict__ csr){
  int e = blockIdx.x*256 + threadIdx.x;
  if (e >= NE) return;
  int d = ei[NE + e];
  int pos = atomicAdd(&cursor[d], 1);
  csr[pos] = ei[e];
}

// ---------------- xa = x @ w1  (no bias yet) ----------------
__global__ void k_lin1(const float* __restrict__ x, const float* __restrict__ w1,
                       float* __restrict__ xa){
  __shared__ float w[FIN*HG];
  int tid = threadIdx.x;
  for (int i = tid; i < FIN*HG; i += 256) w[i] = w1[i];
  __syncthreads();
  int id = blockIdx.x*256 + tid;
  if (id >= NN*HG) return;
  int node = id >> 4, f = id & 15;
  const float* xr = x + (size_t)node*FIN;
  float acc = 0.0f;
#pragma unroll
  for (int k = 0; k < FIN; k++) acc = fmaf(xr[k], w[k*HG + f], acc);
  xa[id] = acc;
}

// ---------------- gather conv (no atomics): 16 lanes per dst node ----------------
__global__ void k_gather(const float* __restrict__ v, const int* __restrict__ csr,
                         const int* __restrict__ eoff, const int* __restrict__ ecnt,
                         const float* __restrict__ dinv, const float* __restrict__ bias,
                         int dorelu, float* __restrict__ out){
  int gid = blockIdx.x*16 + (threadIdx.x >> 4);
  int f = threadIdx.x & 15;
  float dv = dinv[gid];
  float a0 = v[(size_t)gid*HG + f] * dv, a1 = 0.0f, a2 = 0.0f, a3 = 0.0f;
  int o = eoff[gid], n = ecnt[gid];
  int i = 0;
  for (; i + 4 <= n; i += 4){
    int s0 = csr[o+i], s1 = csr[o+i+1], s2 = csr[o+i+2], s3 = csr[o+i+3];
    a0 = fmaf(v[(size_t)s0*HG + f], dinv[s0], a0);
    a1 = fmaf(v[(size_t)s1*HG + f], dinv[s1], a1);
    a2 = fmaf(v[(size_t)s2*HG + f], dinv[s2], a2);
    a3 = fmaf(v[(size_t)s3*HG + f], dinv[s3], a3);
  }
  for (; i < n; i++){
    int s = csr[o+i];
    a0 = fmaf(v[(size_t)s*HG + f], dinv[s], a0);
  }
  float acc = ((a0 + a1) + (a2 + a3)) * dv;
  if (dorelu) acc = fmaxf(acc + bias[f], 0.0f);
  out[(size_t)gid*HG + f] = acc;
}

// ---------------- hb = relu(agg + b1) @ w2 ----------------
__global__ void k_relu_lin(const float* __restrict__ agg, const float* __restrict__ b1,
                           const float* __restrict__ w2, float* __restrict__ hb){
  __shared__ float w[HG*HG];
  __shared__ float bb[HG];
  int tid = threadIdx.x;
  if (tid < HG*HG) w[tid] = w2[tid];
  if (tid < HG) bb[tid] = b1[tid];
  __syncthreads();
  int id = blockIdx.x*256 + tid;
  if (id >= NN*HG) return;
  int node = id >> 4, f = id & 15;
  const float* ar = agg + (size_t)node*HG;
  float acc = 0.0f;
#pragma unroll
  for (int k = 0; k < HG; k++){
    float h = fmaxf(ar[k] + bb[k], 0.0f);
    acc = fmaf(h, w[k*HG + f], acc);
  }
  hb[id] = acc;
}

// ============ BiLSTM: ONE wave per (graph,dir), 2 gate rows per lane ============
// lane layout: sub=lane&31, hi=lane>>5. Gate A = hi*32+sub (i or f),
// gate B = 64+hi*32+sub (g or o). hi lanes own c_sub and h_sub.
// x row held per-lane in registers (uniform vector loads, vmcnt domain,
// double-buffered 2 phases deep). h broadcast via 32-float LDS buffer
// (ds in-order within a wave -> NO barriers anywhere). Weights live in the
// unified VGPR/AGPR file (AGPR-as-src is full rate: R4 evidence).

// ---------------- layer 0 ----------------
__global__ __launch_bounds__(64, 1) void k_lstm0(
    const float* __restrict__ h2in, const int* __restrict__ starts, const int* __restrict__ counts,
    const float* __restrict__ wih, const float* __restrict__ whh,
    const float* __restrict__ bih, const float* __restrict__ bhh,
    float* __restrict__ out0, int* __restrict__ tconv)
{
  const int g = blockIdx.x >> 1, dir = blockIdx.x & 1;
  const int lane = threadIdx.x;
  const int sub = lane & 31, hi = lane >> 5;
  const int gA = hi*32 + sub, gB = 64 + hi*32 + sub;
  float wxA[HG], wxB[HG], uA[HL], uB[HL];
  { const float* p1 = wih + (size_t)dir*128*HG + (size_t)gA*HG;
    const float* p2 = wih + (size_t)dir*128*HG + (size_t)gB*HG;
    const float* p3 = whh + (size_t)dir*128*HL + (size_t)gA*HL;
    const float* p4 = whh + (size_t)dir*128*HL + (size_t)gB*HL;
#pragma unroll
    for (int k = 0; k < HG; k++){ wxA[k] = p1[k]; wxB[k] = p2[k]; }
#pragma unroll
    for (int k = 0; k < HL; k++){ uA[k] = p3[k]; uB[k] = p4[k]; }
  }
  const float pbA = bih[dir*128 + gA] + bhh[dir*128 + gA];
  const float pbB = bih[dir*128 + gB] + bhh[dir*128 + gB];
  int cnt = counts[g]; if (cnt > TS) cnt = TS;
  const int s0 = starts[g];
  float* outg = out0 + (size_t)g*TS*64 + dir*32;
  bool allzero = (__ballot(pbA == 0.0f && pbB == 0.0f) == ~0ull);

  __shared__ __align__(16) float hbuf[HL];
  if (lane < HL) hbuf[lane] = 0.0f;
  __builtin_amdgcn_wave_barrier();

  int t0, dt;
  bool skipall = false;
  if (dir == 0){ t0 = 0; dt = 1; }
  else if (allzero){
    // zero bias + zero input keeps state exactly 0 -> rows >= cnt are 0
    for (int rr = cnt + hi; rr < TS; rr += 2) outg[(size_t)rr*64 + sub] = 0.0f;
    t0 = cnt - 1; dt = -1;
    if (t0 < 0) skipall = true;
  } else { t0 = TS - 1; dt = -1; }

  float c = 0.0f, h = 0.0f;
  bool fwdconv = false;
  float4 XA[4], XB[4];
  int t = t0;

  if (!skipall){
    if (cnt > 0){
      int ta = t0 < 0 ? 0 : (t0 > cnt-1 ? cnt-1 : t0);
      int tb = t0 + dt; tb = tb < 0 ? 0 : (tb > cnt-1 ? cnt-1 : tb);
      const float* pa = h2in + (size_t)(s0 + ta)*HG;
      const float* pb2 = h2in + (size_t)(s0 + tb)*HG;
#pragma unroll
      for (int q = 0; q < 4; q++){ XA[q] = uload4(pa + 4*q); XB[q] = uload4(pb2 + 4*q); }
    }

#define L0STEP(XU) { \
    float a0 = pbA, a1 = 0.0f, b0 = pbB, b1 = 0.0f; \
    const float4* h4 = (const float4*)hbuf; \
    _Pragma("unroll") \
    for (int q = 0; q < 8; q++){ float4 hq = h4[q]; \
      a0 = fmaf(hq.x, uA[4*q+0], a0); a1 = fmaf(hq.y, uA[4*q+1], a1); \
      a0 = fmaf(hq.z, uA[4*q+2], a0); a1 = fmaf(hq.w, uA[4*q+3], a1); \
      b0 = fmaf(hq.x, uB[4*q+0], b0); b1 = fmaf(hq.y, uB[4*q+1], b1); \
      b0 = fmaf(hq.z, uB[4*q+2], b0); b1 = fmaf(hq.w, uB[4*q+3], b1); } \
    if (t < cnt){ \
      _Pragma("unroll") \
      for (int q = 0; q < 4; q++){ float4 xq = XU[q]; \
        a0 = fmaf(xq.x, wxA[4*q+0], a0); a1 = fmaf(xq.y, wxA[4*q+1], a1); \
        a0 = fmaf(xq.z, wxA[4*q+2], a0); a1 = fmaf(xq.w, wxA[4*q+3], a1); \
        b0 = fmaf(xq.x, wxB[4*q+0], b0); b1 = fmaf(xq.y, wxB[4*q+1], b1); \
        b0 = fmaf(xq.z, wxB[4*q+2], b0); b1 = fmaf(xq.w, wxB[4*q+3], b1); } } \
    float aa = a0 + a1, bb = b0 + b1; \
    float sA = sigf(aa); \
    float uu = hi ? bb : (bb + bb); \
    float sv = sigf(uu); \
    float vB = hi ? sv : (sv + sv - 1.0f); \
    float p = sA * vB; \
    float pj = __shfl(p, sub); \
    float cold = c, hold = h; \
    c = fmaf(sA, c, pj); \
    h = vB * tanhfast(c); \
    bool eq = (c == cold) && (h == hold); \
    unsigned long long m = __ballot(hi ? eq : true); \
    if (hi){ hbuf[sub] = h; outg[(size_t)t*64 + sub] = h; } \
    __builtin_amdgcn_wave_barrier(); \
    if (dir == 0 && t >= cnt + 1 && m == ~0ull){ \
      float hval = __shfl(h, 32 + sub); \
      for (int rr = t + 1 + hi; rr < TS; rr += 2) outg[(size_t)rr*64 + sub] = hval; \
      if (lane == 0) tconv[g] = t - 1; \
      fwdconv = true; goto done0; } \
    t += dt; \
    if (dir == 0){ if (t >= TS) goto done0; } else { if (t < 0) goto done0; } \
    if (cnt > 0){ int tp = t + dt; tp = tp < 0 ? 0 : (tp > cnt-1 ? cnt-1 : tp); \
      const float* pp = h2in + (size_t)(s0 + tp)*HG; \
      _Pragma("unroll") \
      for (int q = 0; q < 4; q++) XU[q] = uload4(pp + 4*q); } \
  }

    for (;;){
      L0STEP(XA)
      L0STEP(XB)
    }
done0:;
  }
  if (dir == 0 && !fwdconv && lane == 0) tconv[g] = TS;
}

// ---------------- layer 1 + mean pool ----------------
__global__ __launch_bounds__(64, 1) void k_lstm1(
    const float* __restrict__ gl0, const int* __restrict__ tconv,
    const float* __restrict__ wih, const float* __restrict__ whh,
    const float* __restrict__ bih, const float* __restrict__ bhh,
    float* __restrict__ pooled)
{
  const int g = blockIdx.x >> 1, dir = blockIdx.x & 1;
  const int lane = threadIdx.x;
  const int sub = lane & 31, hi = lane >> 5;
  const int gA = hi*32 + sub, gB = 64 + hi*32 + sub;
  float wxA[64], wxB[64], uA[HL], uB[HL];
  { const float* p1 = wih + (size_t)dir*128*64 + (size_t)gA*64;
    const float* p2 = wih + (size_t)dir*128*64 + (size_t)gB*64;
    const float* p3 = whh + (size_t)dir*128*HL + (size_t)gA*HL;
    const float* p4 = whh + (size_t)dir*128*HL + (size_t)gB*HL;
#pragma unroll
    for (int k = 0; k < 64; k++){ wxA[k] = p1[k]; wxB[k] = p2[k]; }
#pragma unroll
    for (int k = 0; k < HL; k++){ uA[k] = p3[k]; uB[k] = p4[k]; }
  }
  const float pbA = bih[dir*128 + gA] + bhh[dir*128 + gA];
  const float pbB = bih[dir*128 + gB] + bhh[dir*128 + gB];
  const float* gin = gl0 + (size_t)g*TS*64;
  const int tcv = tconv[g];

  __shared__ __align__(16) float hbuf[HL];
  if (lane < HL) hbuf[lane] = 0.0f;
  __builtin_amdgcn_wave_barrier();

  const int t0 = dir ? (TS - 1) : 0, dt = dir ? -1 : 1;
  float c = 0.0f, h = 0.0f, hsum = 0.0f;
  float4 XA[16], XB[16];
  int t = t0;
  {
    int tb = t0 + dt; tb = tb < 0 ? 0 : (tb > TS-1 ? TS-1 : tb);
    const float* pa = gin + (size_t)t0*64;
    const float* pb2 = gin + (size_t)tb*64;
#pragma unroll
    for (int q = 0; q < 16; q++){ XA[q] = uload4(pa + 4*q); XB[q] = uload4(pb2 + 4*q); }
  }

#define L1STEP(XU) { \
    float a0 = pbA, a1 = 0.0f, b0 = pbB, b1 = 0.0f; \
    const float4* h4 = (const float4*)hbuf; \
    _Pragma("unroll") \
    for (int q = 0; q < 8; q++){ float4 hq = h4[q]; \
      a0 = fmaf(hq.x, uA[4*q+0], a0); a1 = fmaf(hq.y, uA[4*q+1], a1); \
      a0 = fmaf(hq.z, uA[4*q+2], a0); a1 = fmaf(hq.w, uA[4*q+3], a1); \
      b0 = fmaf(hq.x, uB[4*q+0], b0); b1 = fmaf(hq.y, uB[4*q+1], b1); \
      b0 = fmaf(hq.z, uB[4*q+2], b0); b1 = fmaf(hq.w, uB[4*q+3], b1); } \
    _Pragma("unroll") \
    for (int q = 0; q < 16; q++){ float4 xq = XU[q]; \
      a0 = fmaf(xq.x, wxA[4*q+0], a0); a1 = fmaf(xq.y, wxA[4*q+1], a1); \
      a0 = fmaf(xq.z, wxA[4*q+2], a0); a1 = fmaf(xq.w, wxA[4*q+3], a1); \
      b0 = fmaf(xq.x, wxB[4*q+0], b0); b1 = fmaf(xq.y, wxB[4*q+1], b1); \
      b0 = fmaf(xq.z, wxB[4*q+2], b0); b1 = fmaf(xq.w, wxB[4*q+3], b1); } \
    float aa = a0 + a1, bb = b0 + b1; \
    float sA = sigf(aa); \
    float uu = hi ? bb : (bb + bb); \
    float sv = sigf(uu); \
    float vB = hi ? sv : (sv + sv - 1.0f); \
    float p = sA * vB; \
    float pj = __shfl(p, sub); \
    float cold = c, hold = h; \
    c = fmaf(sA, c, pj); \
    h = vB * tanhfast(c); \
    hsum += h; \
    bool eq = (c == cold) && (h == hold); \
    unsigned long long m = __ballot(hi ? eq : true); \
    if (hi) hbuf[sub] = h; \
    __builtin_amdgcn_wave_barrier(); \
    if (t >= tcv + 1 && m == ~0ull){ \
      if (dir == 0){ \
        hsum += h * (float)(TS - 1 - t); \
        goto done1; \
      } else { \
        hsum += h * (float)(t - tcv); \
        t = tcv - 1; \
        if (t < 0) goto done1; \
        int rb = t - 1; rb = rb < 0 ? 0 : rb; \
        const float* pa2 = gin + (size_t)t*64; \
        const float* pb3 = gin + (size_t)rb*64; \
        _Pragma("unroll") \
        for (int q = 0; q < 16; q++){ XA[q] = uload4(pa2 + 4*q); XB[q] = uload4(pb3 + 4*q); } \
        goto l1top; } } \
    t += dt; \
    if (dir == 0){ if (t >= TS) goto done1; } else { if (t < 0) goto done1; } \
    { int tp = t + dt; tp = tp < 0 ? 0 : (tp > TS-1 ? TS-1 : tp); \
      const float* pp = gin + (size_t)tp*64; \
      _Pragma("unroll") \
      for (int q = 0; q < 16; q++) XU[q] = uload4(pp + 4*q); } \
  }

l1top:
  for (;;){
    L1STEP(XA)
    L1STEP(XB)
  }
done1:
  if (hi) pooled[(size_t)g*64 + dir*32 + sub] = hsum * (1.0f/(float)TS);
}

// ---------------- FC: out = pooled @ fc_w + fc_b ----------------
__global__ void k_fc(const float* __restrict__ pooled, const float* __restrict__ fcw,
                     const float* __restrict__ fcb, float* __restrict__ out){
  __shared__ float p[64];
  int g = blockIdx.x, cix = threadIdx.x;
  if (cix < 64) p[cix] = pooled[(size_t)g*64 + cix];
  __syncthreads();
  float acc = fcb[cix];
#pragma unroll
  for (int k = 0; k < 64; k++) acc = fmaf(p[k], fcw[k*NC + cix], acc);
  out[(size_t)g*NC + cix] = acc;
}

extern "C" void kernel_launch(void* const* d_in, const int* in_sizes, int n_in,
                              void* d_out, int out_size, void* d_ws, size_t ws_size,
                              hipStream_t stream) {
  const float* x        = (const float*)d_in[0];
  const int*   ei       = (const int*)  d_in[1];
  const int*   batch    = (const int*)  d_in[2];
  const float* gcn_w1   = (const float*)d_in[3];
  const float* gcn_b1   = (const float*)d_in[4];
  const float* gcn_w2   = (const float*)d_in[5];
  const float* gcn_b2   = (const float*)d_in[6];
  const float* l0_wih   = (const float*)d_in[7];
  const float* l0_whh   = (const float*)d_in[8];
  const float* l0_bih   = (const float*)d_in[9];
  const float* l0_bhh   = (const float*)d_in[10];
  const float* l1_wih   = (const float*)d_in[11];
  const float* l1_whh   = (const float*)d_in[12];
  const float* l1_bih   = (const float*)d_in[13];
  const float* l1_bhh   = (const float*)d_in[14];
  const float* fc_w     = (const float*)d_in[15];
  const float* fc_b     = (const float*)d_in[16];
  float* out = (float*)d_out;

  // workspace layout (4B units)
  float* ws   = (float*)d_ws;
  float* B0   = ws;                        // NN*16
  float* B1   = B0 + (size_t)NN*HG;        // NN*16
  float* B2   = B1 + (size_t)NN*HG;        // NN*16
  float* dinv = B2 + (size_t)NN*HG;        // NN
  int*   ecnt   = (int*)(dinv + NN);       // NN
  int*   eoff   = ecnt + NN;               // NN
  int*   cursor = eoff + NN;               // NN
  int*   counts = cursor + NN;             // 512
  int*   starts = counts + NG;             // 512
  int*   tconv  = starts + NG;             // 512
  int*   bsum   = tconv + NG;              // 512
  int*   bstart = bsum + NG;               // 512
  float* pooled = (float*)(bstart + NG);   // 512*64
  int*   csr    = (int*)(pooled + (size_t)NG*64);  // NE
  float* out0   = (float*)(csr + (size_t)NE);      // 512*1024*64
  size_t needed = ((size_t)((float*)out0 - ws) + (size_t)NG*TS*64) * sizeof(float);
  if (ws_size < needed) return;  // fail loudly (poisoned d_out) rather than corrupt

  k_init0 <<<(NN+255)/256, 256, 0, stream>>>(ecnt, counts);
  k_count <<<(NE+255)/256, 256, 0, stream>>>(ei, batch, ecnt, counts);
  k_bsum  <<<NN/256, 256, 0, stream>>>(ecnt, bsum);
  k_scan2 <<<1, NG, 0, stream>>>(counts, starts, bsum, bstart);
  k_eoff  <<<NN/256, 256, 0, stream>>>(ecnt, bstart, eoff, cursor);
  k_dinv  <<<(NN+255)/256, 256, 0, stream>>>(ecnt, dinv);
  k_place <<<(NE+255)/256, 256, 0, stream>>>(ei, cursor, csr);
  k_lin1  <<<(NN*HG)/256, 256, 0, stream>>>(x, gcn_w1, B0);
  k_gather<<<(NN*HG)/256, 256, 0, stream>>>(B0, csr, eoff, ecnt, dinv, gcn_b2, 0, B1);
  k_relu_lin<<<(NN*HG)/256, 256, 0, stream>>>(B1, gcn_b1, gcn_w2, B2);
  k_gather<<<(NN*HG)/256, 256, 0, stream>>>(B2, csr, eoff, ecnt, dinv, gcn_b2, 1, B1);
  k_lstm0 <<<NG*2, 64, 0, stream>>>(B1, starts, counts, l0_wih, l0_whh, l0_bih, l0_bhh, out0, tconv);
  k_lstm1 <<<NG*2, 64, 0, stream>>>(out0, tconv, l1_wih, l1_whh, l1_bih, l1_bhh, pooled);
  k_fc    <<<NG, NC, 0, stream>>>(pooled, fc_w, fc_b, out);
}

// Round 7
// 1551.325 us; speedup vs baseline: 1.2395x; 1.1344x over previous
//
#include <hip/hip_runtime.h>
#include <cstdint>
#include <cstddef>

#define NG 512        // NUM_GRAPHS
#define NN 131072     // N_NODES
#define NE 4194304    // N_EDGES
#define FIN 54        // F_IN
#define HG 16         // H_GCN
#define HL 32         // H_LSTM
#define NC 192        // N_CLASSES
#define TS 1024       // MAX_SEQ_LEN

__device__ __forceinline__ float rcpf(float x){ return __builtin_amdgcn_rcpf(x); }
__device__ __forceinline__ float sigf(float x){ return rcpf(1.0f + __expf(-x)); }
__device__ __forceinline__ float tanhfast(float x){ return 1.0f - 2.0f*rcpf(__expf(2.0f*x) + 1.0f); }

// Wave-uniform row load kept in the VECTOR (vmcnt) domain (R5 lesson: s_load
// shares lgkmcnt with DS, out-of-order -> serializing waits). Same-address
// lanes coalesce to one cacheline fetch + broadcast.
__device__ __forceinline__ float4 uload4(const float* p){
  unsigned long long a = (unsigned long long)p;
  asm volatile("" : "+v"(a));
  return *(const float4*)a;
}

// Raw barrier: drain LDS only (lgkmcnt), NOT vmcnt — __syncthreads drains
// vmcnt(0) which would stall on our in-flight x prefetch every step.
#define WBAR() asm volatile("s_waitcnt lgkmcnt(0)\ns_barrier" ::: "memory")

#define CEPS 1e-6f
#define HEPS 1e-6f

// ---------------- init: ecnt=0, counts=0 ----------------
__global__ void k_init0(int* __restrict__ ecnt, int* __restrict__ counts){
  int i = blockIdx.x*256 + threadIdx.x;
  if (i < NN) ecnt[i] = 0;
  if (i < NG) counts[i] = 0;
}

// ---------------- in-degree histogram + per-graph node counts ----------------
__global__ void k_count(const int* __restrict__ ei, const int* __restrict__ batch,
                        int* __restrict__ ecnt, int* __restrict__ counts){
  int i = blockIdx.x*256 + threadIdx.x;
  if (i < NE) atomicAdd(&ecnt[ei[NE + i]], 1);
  if (i < NN) atomicAdd(&counts[batch[i]], 1);
}

// ---------------- per-256-chunk sums of ecnt ----------------
__global__ void k_bsum(const int* __restrict__ ecnt, int* __restrict__ bsum){
  __shared__ int s[256];
  int t = threadIdx.x;
  s[t] = ecnt[blockIdx.x*256 + t];
  __syncthreads();
  for (int o = 128; o > 0; o >>= 1){ if (t < o) s[t] += s[t+o]; __syncthreads(); }
  if (t == 0) bsum[blockIdx.x] = s[0];
}

// ---------------- dual exclusive scan of two 512-arrays (1 block, 512 thr) ----------------
__global__ void k_scan2(const int* __restrict__ a, int* __restrict__ ax,
                        const int* __restrict__ b, int* __restrict__ bx){
  __shared__ int s[NG];
  int t = threadIdx.x;
  s[t] = a[t]; __syncthreads();
  for (int o = 1; o < NG; o <<= 1){ int v = (t >= o) ? s[t-o] : 0; __syncthreads(); s[t] += v; __syncthreads(); }
  ax[t] = s[t] - a[t];
  __syncthreads();
  s[t] = b[t]; __syncthreads();
  for (int o = 1; o < NG; o <<= 1){ int v = (t >= o) ? s[t-o] : 0; __syncthreads(); s[t] += v; __syncthreads(); }
  bx[t] = s[t] - b[t];
}

// ---------------- per-node edge offsets (block-local scan + chunk base) ----------------
__global__ void k_eoff(const int* __restrict__ ecnt, const int* __restrict__ bstart,
                       int* __restrict__ eoff, int* __restrict__ cursor){
  __shared__ int s[256];
  int t = threadIdx.x, i = blockIdx.x*256 + t;
  int v = ecnt[i];
  s[t] = v; __syncthreads();
  for (int o = 1; o < 256; o <<= 1){ int u = (t >= o) ? s[t-o] : 0; __syncthreads(); s[t] += u; __syncthreads(); }
  int ex = s[t] - v + bstart[blockIdx.x];
  eoff[i] = ex; cursor[i] = ex;
}

__global__ void k_dinv(const int* __restrict__ ecnt, float* __restrict__ dinv){
  int i = blockIdx.x*256 + threadIdx.x;
  if (i < NN) dinv[i] = 1.0f / sqrtf((float)(ecnt[i] + 1));  // deg = indeg + self-loop >= 1
}

// ---------------- CSR placement: csr[eoff[dst]..] = src ----------------
__global__ void k_place(const int* __restrict__ ei, int* __restrict__ cursor, int* __restrict__ csr){
  int e = blockIdx.x*256 + threadIdx.x;
  if (e >= NE) return;
  int d = ei[NE + e];
  int pos = atomicAdd(&cursor[d], 1);
  csr[pos] = ei[e];
}

// ---------------- xa = x @ w1 : stage x rows via LDS (kill 16x re-read) ----------------
__global__ void k_lin1(const float* __restrict__ x, const float* __restrict__ w1,
                       float* __restrict__ xa){
  __shared__ float w[FIN*HG];       // 864
  __shared__ float xs[16][FIN+2];   // pad to 56
  int tid = threadIdx.x;
  for (int i = tid; i < FIN*HG; i += 256) w[i] = w1[i];
  // 16 rows x 54 floats = 864 floats = 216 float4, contiguous & 16B-aligned
  const float4* gx = (const float4*)(x + (size_t)blockIdx.x*16*FIN);
  if (tid < 216){
    float4 v4 = gx[tid];
    int fi = tid*4;
#pragma unroll
    for (int e = 0; e < 4; e++){
      int idx = fi + e;
      xs[idx/FIN][idx%FIN] = ((const float*)&v4)[e];
    }
  }
  __syncthreads();
  int node = tid >> 4, f = tid & 15;
  const float* xr = xs[node];
  float acc = 0.0f;
#pragma unroll
  for (int k = 0; k < FIN; k++) acc = fmaf(xr[k], w[k*HG + f], acc);
  xa[((size_t)blockIdx.x*16 + node)*HG + f] = acc;
}

// ---------------- gather conv (no atomics): 16 lanes per dst node ----------------
__global__ void k_gather(const float* __restrict__ v, const int* __restrict__ csr,
                         const int* __restrict__ eoff, const int* __restrict__ ecnt,
                         const float* __restrict__ dinv, const float* __restrict__ bias,
                         int dorelu, float* __restrict__ out){
  int gid = blockIdx.x*16 + (threadIdx.x >> 4);
  int f = threadIdx.x & 15;
  float dv = dinv[gid];
  float a0 = v[(size_t)gid*HG + f] * dv, a1 = 0.0f, a2 = 0.0f, a3 = 0.0f;
  int o = eoff[gid], n = ecnt[gid];
  int i = 0;
  for (; i + 8 <= n; i += 8){
    int s0 = csr[o+i],   s1 = csr[o+i+1], s2 = csr[o+i+2], s3 = csr[o+i+3];
    int s4 = csr[o+i+4], s5 = csr[o+i+5], s6 = csr[o+i+6], s7 = csr[o+i+7];
    a0 = fmaf(v[(size_t)s0*HG + f], dinv[s0], a0);
    a1 = fmaf(v[(size_t)s1*HG + f], dinv[s1], a1);
    a2 = fmaf(v[(size_t)s2*HG + f], dinv[s2], a2);
    a3 = fmaf(v[(size_t)s3*HG + f], dinv[s3], a3);
    a0 = fmaf(v[(size_t)s4*HG + f], dinv[s4], a0);
    a1 = fmaf(v[(size_t)s5*HG + f], dinv[s5], a1);
    a2 = fmaf(v[(size_t)s6*HG + f], dinv[s6], a2);
    a3 = fmaf(v[(size_t)s7*HG + f], dinv[s7], a3);
  }
  for (; i + 4 <= n; i += 4){
    int s0 = csr[o+i], s1 = csr[o+i+1], s2 = csr[o+i+2], s3 = csr[o+i+3];
    a0 = fmaf(v[(size_t)s0*HG + f], dinv[s0], a0);
    a1 = fmaf(v[(size_t)s1*HG + f], dinv[s1], a1);
    a2 = fmaf(v[(size_t)s2*HG + f], dinv[s2], a2);
    a3 = fmaf(v[(size_t)s3*HG + f], dinv[s3], a3);
  }
  for (; i < n; i++){
    int s = csr[o+i];
    a0 = fmaf(v[(size_t)s*HG + f], dinv[s], a0);
  }
  float acc = ((a0 + a1) + (a2 + a3)) * dv;
  if (dorelu) acc = fmaxf(acc + bias[f], 0.0f);
  out[(size_t)gid*HG + f] = acc;
}

// ---------------- hb = relu(agg + b1) @ w2 ----------------
__global__ void k_relu_lin(const float* __restrict__ agg, const float* __restrict__ b1,
                           const float* __restrict__ w2, float* __restrict__ hb){
  __shared__ float w[HG*HG];
  __shared__ float bb[HG];
  int tid = threadIdx.x;
  if (tid < HG*HG) w[tid] = w2[tid];
  if (tid < HG) bb[tid] = b1[tid];
  __syncthreads();
  int id = blockIdx.x*256 + tid;
  if (id >= NN*HG) return;
  int node = id >> 4, f = id & 15;
  const float* ar = agg + (size_t)node*HG;
  float acc = 0.0f;
#pragma unroll
  for (int k = 0; k < HG; k++){
    float h = fmaxf(ar[k] + bb[k], 0.0f);
    acc = fmaf(h, w[k*HG + f], acc);
  }
  hb[id] = acc;
}

// ============ BiLSTM: 2 waves per (graph,dir), ONE gate row per thread ============
// wave0: i (lanes 0-31), g (lanes 32-63). wave1: f (lanes 0-31, owns c),
// o (lanes 32-63, owns h). x rows in per-thread registers via uload4 (vmcnt),
// single-buffered, prefetched right after consumption. h via LDS (b128).
// Raw lgkm-only barriers so x prefetch stays in flight across them.
// Convergence: eps-based (bitwise never fires: ~1-ulp limit cycles).

// ---------------- layer 0 ----------------
__global__ __launch_bounds__(128, 2) void k_lstm0(
    const float* __restrict__ h2in, const int* __restrict__ starts, const int* __restrict__ counts,
    const float* __restrict__ wih, const float* __restrict__ whh,
    const float* __restrict__ bih, const float* __restrict__ bhh,
    float* __restrict__ out0, int* __restrict__ tconv)
{
  const int g = blockIdx.x >> 1, dir = blockIdx.x & 1;
  const int tid = threadIdx.x;
  const int wv = tid >> 6, lane = tid & 63;
  const int sub = lane & 31, hi = lane >> 5;
  const int r = wv ? (hi ? 96 + sub : 32 + sub) : (hi ? 64 + sub : sub);
  float wr[HG], ur[HL];
  { const float* wp = wih + (size_t)dir*128*HG + (size_t)r*HG;
    const float* up = whh + (size_t)dir*128*HL + (size_t)r*HL;
#pragma unroll
    for (int k = 0; k < HG; k++) wr[k] = wp[k];
#pragma unroll
    for (int k = 0; k < HL; k++) ur[k] = up[k];
  }
  const float pb = bih[dir*128 + r] + bhh[dir*128 + r];
  int cnt = counts[g]; if (cnt > TS) cnt = TS;
  const int s0 = starts[g];
  float* outg = out0 + (size_t)g*TS*64 + dir*32;

  __shared__ __align__(16) float hbuf[2][HL];
  __shared__ __align__(16) float pbuf[HL];
  __shared__ int flagbuf;
  __shared__ unsigned long long azm[2];

  unsigned long long bz = __ballot(pb == 0.0f);
  if (lane == 0) azm[wv] = bz;
  if (tid < HL) hbuf[0][tid] = 0.0f;
  if (tid == 0) flagbuf = 0;
  WBAR();
  bool allzero = (azm[0] == ~0ull) && (azm[1] == ~0ull);

  int t0, dt;
  bool skipall = false;
  if (dir == 0){ t0 = 0; dt = 1; }
  else if (allzero){
    // zero bias + zero input keeps state exactly 0 -> rows >= cnt are 0
    for (int rr = cnt + (tid >> 5); rr < TS; rr += 4) outg[(size_t)rr*64 + sub] = 0.0f;
    t0 = cnt - 1; dt = -1;
    if (t0 < 0) skipall = true;
  } else { t0 = TS - 1; dt = -1; }

  float c = 0.0f, h = 0.0f;
  bool fwdconv = false;
  float4 X[4];
#pragma unroll
  for (int q = 0; q < 4; q++) X[q] = make_float4(0,0,0,0);
  int t = t0, cur = 0;

  if (!skipall){
    if (cnt > 0){
      int ta = t0 < 0 ? 0 : (t0 > cnt-1 ? cnt-1 : t0);
      const float* pa = h2in + (size_t)(s0 + ta)*HG;
#pragma unroll
      for (int q = 0; q < 4; q++) X[q] = uload4(pa + 4*q);
    }
    for (;;){
      int nxt = cur ^ 1;
      float a0 = pb, a1 = 0.0f, a2 = 0.0f, a3 = 0.0f;
      if (t < cnt){
#pragma unroll
        for (int q = 0; q < 4; q++){ float4 xq = X[q];
          a0 = fmaf(xq.x, wr[4*q+0], a0); a1 = fmaf(xq.y, wr[4*q+1], a1);
          a2 = fmaf(xq.z, wr[4*q+2], a2); a3 = fmaf(xq.w, wr[4*q+3], a3); }
      }
      // prefetch next row (vmcnt; stays in flight across raw barriers)
      if (cnt > 0){
        int tp = t + dt; tp = tp < 0 ? 0 : (tp > cnt-1 ? cnt-1 : tp);
        const float* pp = h2in + (size_t)(s0 + tp)*HG;
#pragma unroll
        for (int q = 0; q < 4; q++) X[q] = uload4(pp + 4*q);
      }
      { const float4* h4 = (const float4*)hbuf[cur];
#pragma unroll
        for (int q = 0; q < HL/4; q++){ float4 hq = h4[q];
          a0 = fmaf(hq.x, ur[4*q+0], a0); a1 = fmaf(hq.y, ur[4*q+1], a1);
          a2 = fmaf(hq.z, ur[4*q+2], a2); a3 = fmaf(hq.w, ur[4*q+3], a3); }
      }
      float a = (a0 + a1) + (a2 + a3);
      float sv1 = 0.0f;
      if (wv == 0){
        float u  = hi ? (a + a) : a;
        float sv = sigf(u);
        float v  = hi ? (sv + sv - 1.0f) : sv;   // hi: tanh(g); lo: sig(i)
        float gv = __shfl(v, 32 + sub);
        float p  = v * gv;                        // lanes<32: sig(i)*tanh(g)
        if (lane < HL) pbuf[lane] = p;
      } else {
        sv1 = sigf(a);                            // f or o
      }
      WBAR();  // barrier1: pbuf visible
      if (wv == 1){
        float cn = 0.0f, tcn = 0.0f;
        bool eq;
        if (!hi){
          cn = fmaf(sv1, c, pbuf[sub]);
          eq = fabsf(cn - c) <= CEPS*(1.0f + fabsf(cn));
          c = cn; tcn = tanhfast(cn);
        }
        float tcs = __shfl(tcn, sub);
        if (hi){
          float hn = sv1 * tcs;
          eq = fabsf(hn - h) <= HEPS;
          h = hn;
          hbuf[nxt][sub] = h;
          outg[(size_t)t*64 + sub] = h;
        }
        unsigned long long m = __ballot(eq);
        bool conv = (m == ~0ull) && (dir == 0) && (t >= cnt + 1);
        if (lane == 0) flagbuf = conv ? 1 : 0;
      }
      WBAR();  // barrier2: hbuf[nxt], flag visible
      if (flagbuf){
        // state (approx) fixed under constant zero input: tail rows = h*
        float hval = hbuf[nxt][sub];
        for (int rr = t + 1 + (tid >> 5); rr < TS; rr += 4) outg[(size_t)rr*64 + sub] = hval;
        if (tid == 64) tconv[g] = t - 1;   // rows t-1.. constant (bitwise, by construction)
        fwdconv = true;
        break;
      }
      t += dt;
      if (dir == 0){ if (t >= TS) break; } else { if (t < 0) break; }
      cur = nxt;
    }
  }
  if (dir == 0 && !fwdconv && tid == 64) tconv[g] = TS;
}

// ---------------- layer 1 + mean pool ----------------
__global__ __launch_bounds__(128, 2) void k_lstm1(
    const float* __restrict__ gl0, const int* __restrict__ tconv,
    const float* __restrict__ wih, const float* __restrict__ whh,
    const float* __restrict__ bih, const float* __restrict__ bhh,
    float* __restrict__ pooled)
{
  const int g = blockIdx.x >> 1, dir = blockIdx.x & 1;
  const int tid = threadIdx.x;
  const int wv = tid >> 6, lane = tid & 63;
  const int sub = lane & 31, hi = lane >> 5;
  const int r = wv ? (hi ? 96 + sub : 32 + sub) : (hi ? 64 + sub : sub);
  float wr[64], ur[HL];
  { const float* wp = wih + (size_t)dir*128*64 + (size_t)r*64;
    const float* up = whh + (size_t)dir*128*HL + (size_t)r*HL;
#pragma unroll
    for (int k = 0; k < 64; k++) wr[k] = wp[k];
#pragma unroll
    for (int k = 0; k < HL; k++) ur[k] = up[k];
  }
  const float pb = bih[dir*128 + r] + bhh[dir*128 + r];
  const float* gin = gl0 + (size_t)g*TS*64;
  const int tcv = tconv[g];

  __shared__ __align__(16) float hbuf[2][HL];
  __shared__ __align__(16) float pbuf[HL];
  __shared__ int flagbuf;

  if (tid < HL) hbuf[0][tid] = 0.0f;
  if (tid == 0) flagbuf = 0;
  WBAR();

  const int t0 = dir ? (TS - 1) : 0, dt = dir ? -1 : 1;
  float c = 0.0f, h = 0.0f, hsum = 0.0f;
  float4 X[16];
  int t = t0, cur = 0;
  { const float* pa = gin + (size_t)t0*64;
#pragma unroll
    for (int q = 0; q < 16; q++) X[q] = uload4(pa + 4*q);
  }

  for (;;){
    int nxt = cur ^ 1;
    float a0 = pb, a1 = 0.0f, a2 = 0.0f, a3 = 0.0f;
#pragma unroll
    for (int q = 0; q < 16; q++){ float4 xq = X[q];
      a0 = fmaf(xq.x, wr[4*q+0], a0); a1 = fmaf(xq.y, wr[4*q+1], a1);
      a2 = fmaf(xq.z, wr[4*q+2], a2); a3 = fmaf(xq.w, wr[4*q+3], a3); }
    // prefetch next row
    { int tp = t + dt; tp = tp < 0 ? 0 : (tp > TS-1 ? TS-1 : tp);
      const float* pp = gin + (size_t)tp*64;
#pragma unroll
      for (int q = 0; q < 16; q++) X[q] = uload4(pp + 4*q);
    }
    { const float4* h4 = (const float4*)hbuf[cur];
#pragma unroll
      for (int q = 0; q < HL/4; q++){ float4 hq = h4[q];
        a0 = fmaf(hq.x, ur[4*q+0], a0); a1 = fmaf(hq.y, ur[4*q+1], a1);
        a2 = fmaf(hq.z, ur[4*q+2], a2); a3 = fmaf(hq.w, ur[4*q+3], a3); }
    }
    float a = (a0 + a1) + (a2 + a3);
    float sv1 = 0.0f;
    if (wv == 0){
      float u  = hi ? (a + a) : a;
      float sv = sigf(u);
      float v  = hi ? (sv + sv - 1.0f) : sv;
      float gv = __shfl(v, 32 + sub);
      float p  = v * gv;
      if (lane < HL) pbuf[lane] = p;
    } else {
      sv1 = sigf(a);
    }
    WBAR();  // barrier1
    if (wv == 1){
      float cn = 0.0f, tcn = 0.0f;
      bool eq;
      if (!hi){
        cn = fmaf(sv1, c, pbuf[sub]);
        eq = fabsf(cn - c) <= CEPS*(1.0f + fabsf(cn));
        c = cn; tcn = tanhfast(cn);
      }
      float tcs = __shfl(tcn, sub);
      if (hi){
        float hn = sv1 * tcs;
        eq = fabsf(hn - h) <= HEPS;
        h = hn;
        hsum += h;
        hbuf[nxt][sub] = h;
      }
      unsigned long long m = __ballot(eq);
      bool conv = (m == ~0ull) && (t >= tcv + 1);
      if (lane == 0) flagbuf = conv ? 1 : 0;
    }
    WBAR();  // barrier2
    if (flagbuf){
      if (dir == 0){
        // input const for all remaining t, state fixed -> close the mean
        if (wv == 1 && hi) hsum += h * (float)(TS - 1 - t);
        break;
      } else {
        // rows [tcv, t-1] equal current input; state fixed -> h* repeats
        if (wv == 1 && hi) hsum += h * (float)(t - tcv);
        t = tcv - 1;
        if (t < 0) break;
        const float* pa2 = gin + (size_t)t*64;
#pragma unroll
        for (int q = 0; q < 16; q++) X[q] = uload4(pa2 + 4*q);
        cur = nxt;
        continue;
      }
    }
    t += dt;
    if (dir == 0){ if (t >= TS) break; } else { if (t < 0) break; }
    cur = nxt;
  }
  if (wv == 1 && hi) pooled[(size_t)g*64 + dir*32 + sub] = hsum * (1.0f/(float)TS);
}

// ---------------- FC: out = pooled @ fc_w + fc_b ----------------
__global__ void k_fc(const float* __restrict__ pooled, const float* __restrict__ fcw,
                     const float* __restrict__ fcb, float* __restrict__ out){
  __shared__ float p[64];
  int g = blockIdx.x, cix = threadIdx.x;
  if (cix < 64) p[cix] = pooled[(size_t)g*64 + cix];
  __syncthreads();
  float acc = fcb[cix];
#pragma unroll
  for (int k = 0; k < 64; k++) acc = fmaf(p[k], fcw[k*NC + cix], acc);
  out[(size_t)g*NC + cix] = acc;
}

extern "C" void kernel_launch(void* const* d_in, const int* in_sizes, int n_in,
                              void* d_out, int out_size, void* d_ws, size_t ws_size,
                              hipStream_t stream) {
  const float* x        = (const float*)d_in[0];
  const int*   ei       = (const int*)  d_in[1];
  const int*   batch    = (const int*)  d_in[2];
  const float* gcn_w1   = (const float*)d_in[3];
  const float* gcn_b1   = (const float*)d_in[4];
  const float* gcn_w2   = (const float*)d_in[5];
  const float* gcn_b2   = (const float*)d_in[6];
  const float* l0_wih   = (const float*)d_in[7];
  const float* l0_whh   = (const float*)d_in[8];
  const float* l0_bih   = (const float*)d_in[9];
  const float* l0_bhh   = (const float*)d_in[10];
  const float* l1_wih   = (const float*)d_in[11];
  const float* l1_whh   = (const float*)d_in[12];
  const float* l1_bih   = (const float*)d_in[13];
  const float* l1_bhh   = (const float*)d_in[14];
  const float* fc_w     = (const float*)d_in[15];
  const float* fc_b     = (const float*)d_in[16];
  float* out = (float*)d_out;

  // workspace layout (4B units)
  float* ws   = (float*)d_ws;
  float* B0   = ws;                        // NN*16
  float* B1   = B0 + (size_t)NN*HG;        // NN*16
  float* B2   = B1 + (size_t)NN*HG;        // NN*16
  float* dinv = B2 + (size_t)NN*HG;        // NN
  int*   ecnt   = (int*)(dinv + NN);       // NN
  int*   eoff   = ecnt + NN;               // NN
  int*   cursor = eoff + NN;               // NN
  int*   counts = cursor + NN;             // 512
  int*   starts = counts + NG;             // 512
  int*   tconv  = starts + NG;             // 512
  int*   bsum   = tconv + NG;              // 512
  int*   bstart = bsum + NG;               // 512
  float* pooled = (float*)(bstart + NG);   // 512*64
  int*   csr    = (int*)(pooled + (size_t)NG*64);  // NE
  float* out0   = (float*)(csr + (size_t)NE);      // 512*1024*64
  size_t needed = ((size_t)((float*)out0 - ws) + (size_t)NG*TS*64) * sizeof(float);
  if (ws_size < needed) return;  // fail loudly (poisoned d_out) rather than corrupt

  k_init0 <<<(NN+255)/256, 256, 0, stream>>>(ecnt, counts);
  k_count <<<(NE+255)/256, 256, 0, stream>>>(ei, batch, ecnt, counts);
  k_bsum  <<<NN/256, 256, 0, stream>>>(ecnt, bsum);
  k_scan2 <<<1, NG, 0, stream>>>(counts, starts, bsum, bstart);
  k_eoff  <<<NN/256, 256, 0, stream>>>(ecnt, bstart, eoff, cursor);
  k_dinv  <<<(NN+255)/256, 256, 0, stream>>>(ecnt, dinv);
  k_place <<<(NE+255)/256, 256, 0, stream>>>(ei, cursor, csr);
  k_lin1  <<<NN/16, 256, 0, stream>>>(x, gcn_w1, B0);
  k_gather<<<(NN*HG)/256, 256, 0, stream>>>(B0, csr, eoff, ecnt, dinv, gcn_b2, 0, B1);
  k_relu_lin<<<(NN*HG)/256, 256, 0, stream>>>(B1, gcn_b1, gcn_w2, B2);
  k_gather<<<(NN*HG)/256, 256, 0, stream>>>(B2, csr, eoff, ecnt, dinv, gcn_b2, 1, B1);
  k_lstm0 <<<NG*2, 128, 0, stream>>>(B1, starts, counts, l0_wih, l0_whh, l0_bih, l0_bhh, out0, tconv);
  k_lstm1 <<<NG*2, 128, 0, stream>>>(out0, tconv, l1_wih, l1_whh, l1_bih, l1_bhh, pooled);
  k_fc    <<<NG, NC, 0, stream>>>(pooled, fc_w, fc_b, out);
}

// Round 8
// 1451.596 us; speedup vs baseline: 1.3246x; 1.0687x over previous
//
#include <hip/hip_runtime.h>
#include <cstdint>
#include <cstddef>

#define NG 512        // NUM_GRAPHS
#define NN 131072     // N_NODES
#define NE 4194304    // N_EDGES
#define FIN 54        // F_IN
#define HG 16         // H_GCN
#define HL 32         // H_LSTM
#define NC 192        // N_CLASSES
#define TS 1024       // MAX_SEQ_LEN

__device__ __forceinline__ float rcpf(float x){ return __builtin_amdgcn_rcpf(x); }
__device__ __forceinline__ float sigf(float x){ return rcpf(1.0f + __expf(-x)); }
__device__ __forceinline__ float tanhfast(float x){ return 1.0f - 2.0f*rcpf(__expf(2.0f*x) + 1.0f); }

// Wave-uniform row load kept in the VECTOR (vmcnt) domain (R5 lesson: s_load
// shares lgkmcnt with DS, out-of-order -> serializing waits).
__device__ __forceinline__ float4 uload4(const float* p){
  unsigned long long a = (unsigned long long)p;
  asm volatile("" : "+v"(a));
  return *(const float4*)a;
}

// Raw barrier: drain LDS only (lgkmcnt), NOT vmcnt — keeps x prefetch in flight.
#define WBAR() asm volatile("s_waitcnt lgkmcnt(0)\ns_barrier" ::: "memory")

#define CEPS 1e-6f
#define HEPS 1e-6f

// ---------------- init: ecnt=0, counts=0 ----------------
__global__ void k_init0(int* __restrict__ ecnt, int* __restrict__ counts){
  int i = blockIdx.x*256 + threadIdx.x;
  if (i < NN) ecnt[i] = 0;
  if (i < NG) counts[i] = 0;
}

// ---------------- in-degree histogram + per-graph node counts ----------------
__global__ void k_count(const int* __restrict__ ei, const int* __restrict__ batch,
                        int* __restrict__ ecnt, int* __restrict__ counts){
  int i = blockIdx.x*256 + threadIdx.x;
  if (i < NE) atomicAdd(&ecnt[ei[NE + i]], 1);
  if (i < NN) atomicAdd(&counts[batch[i]], 1);
}

// ---------------- per-256-chunk sums of ecnt ----------------
__global__ void k_bsum(const int* __restrict__ ecnt, int* __restrict__ bsum){
  __shared__ int s[256];
  int t = threadIdx.x;
  s[t] = ecnt[blockIdx.x*256 + t];
  __syncthreads();
  for (int o = 128; o > 0; o >>= 1){ if (t < o) s[t] += s[t+o]; __syncthreads(); }
  if (t == 0) bsum[blockIdx.x] = s[0];
}

// ---------------- dual exclusive scan of two 512-arrays (1 block, 512 thr) ----------------
__global__ void k_scan2(const int* __restrict__ a, int* __restrict__ ax,
                        const int* __restrict__ b, int* __restrict__ bx){
  __shared__ int s[NG];
  int t = threadIdx.x;
  s[t] = a[t]; __syncthreads();
  for (int o = 1; o < NG; o <<= 1){ int v = (t >= o) ? s[t-o] : 0; __syncthreads(); s[t] += v; __syncthreads(); }
  ax[t] = s[t] - a[t];
  __syncthreads();
  s[t] = b[t]; __syncthreads();
  for (int o = 1; o < NG; o <<= 1){ int v = (t >= o) ? s[t-o] : 0; __syncthreads(); s[t] += v; __syncthreads(); }
  bx[t] = s[t] - b[t];
}

// ---------------- per-node edge offsets (block-local scan + chunk base) ----------------
__global__ void k_eoff(const int* __restrict__ ecnt, const int* __restrict__ bstart,
                       int* __restrict__ eoff, int* __restrict__ cursor){
  __shared__ int s[256];
  int t = threadIdx.x, i = blockIdx.x*256 + t;
  int v = ecnt[i];
  s[t] = v; __syncthreads();
  for (int o = 1; o < 256; o <<= 1){ int u = (t >= o) ? s[t-o] : 0; __syncthreads(); s[t] += u; __syncthreads(); }
  int ex = s[t] - v + bstart[blockIdx.x];
  eoff[i] = ex; cursor[i] = ex;
}

__global__ void k_dinv(const int* __restrict__ ecnt, float* __restrict__ dinv){
  int i = blockIdx.x*256 + threadIdx.x;
  if (i < NN) dinv[i] = 1.0f / sqrtf((float)(ecnt[i] + 1));  // deg = indeg + self-loop >= 1
}

// ---------------- CSR placement: csr[eoff[dst]..] = src ----------------
__global__ void k_place(const int* __restrict__ ei, int* __restrict__ cursor, int* __restrict__ csr){
  int e = blockIdx.x*256 + threadIdx.x;
  if (e >= NE) return;
  int d = ei[NE + e];
  int pos = atomicAdd(&cursor[d], 1);
  csr[pos] = ei[e];
}

// ---------------- xa = x @ w1 : stage x rows via LDS ----------------
__global__ void k_lin1(const float* __restrict__ x, const float* __restrict__ w1,
                       float* __restrict__ xa){
  __shared__ float w[FIN*HG];       // 864
  __shared__ float xs[16][FIN+2];   // pad to 56
  int tid = threadIdx.x;
  for (int i = tid; i < FIN*HG; i += 256) w[i] = w1[i];
  const float4* gx = (const float4*)(x + (size_t)blockIdx.x*16*FIN);
  if (tid < 216){
    float4 v4 = gx[tid];
    int fi = tid*4;
#pragma unroll
    for (int e = 0; e < 4; e++){
      int idx = fi + e;
      xs[idx/FIN][idx%FIN] = ((const float*)&v4)[e];
    }
  }
  __syncthreads();
  int node = tid >> 4, f = tid & 15;
  const float* xr = xs[node];
  float acc = 0.0f;
#pragma unroll
  for (int k = 0; k < FIN; k++) acc = fmaf(xr[k], w[k*HG + f], acc);
  xa[((size_t)blockIdx.x*16 + node)*HG + f] = acc;
}

// ---------------- gather conv (no atomics): 16 lanes per dst node ----------------
__global__ void k_gather(const float* __restrict__ v, const int* __restrict__ csr,
                         const int* __restrict__ eoff, const int* __restrict__ ecnt,
                         const float* __restrict__ dinv, const float* __restrict__ bias,
                         int dorelu, float* __restrict__ out){
  int gid = blockIdx.x*16 + (threadIdx.x >> 4);
  int f = threadIdx.x & 15;
  float dv = dinv[gid];
  float a0 = v[(size_t)gid*HG + f] * dv, a1 = 0.0f, a2 = 0.0f, a3 = 0.0f;
  int o = eoff[gid], n = ecnt[gid];
  int i = 0;
  for (; i + 8 <= n; i += 8){
    int s0 = csr[o+i],   s1 = csr[o+i+1], s2 = csr[o+i+2], s3 = csr[o+i+3];
    int s4 = csr[o+i+4], s5 = csr[o+i+5], s6 = csr[o+i+6], s7 = csr[o+i+7];
    a0 = fmaf(v[(size_t)s0*HG + f], dinv[s0], a0);
    a1 = fmaf(v[(size_t)s1*HG + f], dinv[s1], a1);
    a2 = fmaf(v[(size_t)s2*HG + f], dinv[s2], a2);
    a3 = fmaf(v[(size_t)s3*HG + f], dinv[s3], a3);
    a0 = fmaf(v[(size_t)s4*HG + f], dinv[s4], a0);
    a1 = fmaf(v[(size_t)s5*HG + f], dinv[s5], a1);
    a2 = fmaf(v[(size_t)s6*HG + f], dinv[s6], a2);
    a3 = fmaf(v[(size_t)s7*HG + f], dinv[s7], a3);
  }
  for (; i + 4 <= n; i += 4){
    int s0 = csr[o+i], s1 = csr[o+i+1], s2 = csr[o+i+2], s3 = csr[o+i+3];
    a0 = fmaf(v[(size_t)s0*HG + f], dinv[s0], a0);
    a1 = fmaf(v[(size_t)s1*HG + f], dinv[s1], a1);
    a2 = fmaf(v[(size_t)s2*HG + f], dinv[s2], a2);
    a3 = fmaf(v[(size_t)s3*HG + f], dinv[s3], a3);
  }
  for (; i < n; i++){
    int s = csr[o+i];
    a0 = fmaf(v[(size_t)s*HG + f], dinv[s], a0);
  }
  float acc = ((a0 + a1) + (a2 + a3)) * dv;
  if (dorelu) acc = fmaxf(acc + bias[f], 0.0f);
  out[(size_t)gid*HG + f] = acc;
}

// ---------------- hb = relu(agg + b1) @ w2 ----------------
__global__ void k_relu_lin(const float* __restrict__ agg, const float* __restrict__ b1,
                           const float* __restrict__ w2, float* __restrict__ hb){
  __shared__ float w[HG*HG];
  __shared__ float bb[HG];
  int tid = threadIdx.x;
  if (tid < HG*HG) w[tid] = w2[tid];
  if (tid < HG) bb[tid] = b1[tid];
  __syncthreads();
  int id = blockIdx.x*256 + tid;
  if (id >= NN*HG) return;
  int node = id >> 4, f = id & 15;
  const float* ar = agg + (size_t)node*HG;
  float acc = 0.0f;
#pragma unroll
  for (int k = 0; k < HG; k++){
    float h = fmaxf(ar[k] + bb[k], 0.0f);
    acc = fmaf(h, w[k*HG + f], acc);
  }
  hb[id] = acc;
}

// ============ BiLSTM: 2 waves/chain, 1 barrier/step, redundant c,h ============
// Row map: wave0 lo = i_sub, wave0 hi = g_sub, wave1 lo = f_sub, wave1 hi = o_sub.
// Per step: each wave computes its 64 gate ACTIVATIONS -> ping-pong LDS; ONE
// WBAR; both waves gather (2 shfl own + 2 LDS foreign) and compute c,h
// REDUNDANTLY (bitwise identical -> wave-local convergence ballot, no flag).
// h lives in per-wave private LDS (within-wave DS order -> no barrier).
// x rows per-lane in registers via uload4 (vmcnt domain, prefetch 1 ahead).

// ---------------- layer 0 ----------------
__global__ __launch_bounds__(128, 2) void k_lstm0(
    const float* __restrict__ h2in, const int* __restrict__ starts, const int* __restrict__ counts,
    const float* __restrict__ wih, const float* __restrict__ whh,
    const float* __restrict__ bih, const float* __restrict__ bhh,
    float* __restrict__ out0, int* __restrict__ tconv)
{
  const int g = blockIdx.x >> 1, dir = blockIdx.x & 1;
  const int tid = threadIdx.x;
  const int wv = tid >> 6, lane = tid & 63;
  const int sub = lane & 31, hi = lane >> 5;
  const int r = (hi ? 64 : 0) + (wv ? 32 : 0) + sub;   // i/g/f/o row
  float wx[HG], wh[HL];
  { const float* wp = wih + (size_t)dir*128*HG + (size_t)r*HG;
    const float* up = whh + (size_t)dir*128*HL + (size_t)r*HL;
#pragma unroll
    for (int k = 0; k < HG; k++) wx[k] = wp[k];
#pragma unroll
    for (int k = 0; k < HL; k++) wh[k] = up[k];
  }
  const float pb = bih[dir*128 + r] + bhh[dir*128 + r];
  int cnt = counts[g]; if (cnt > TS) cnt = TS;
  const int s0 = starts[g];
  float* outg = out0 + (size_t)g*TS*64 + dir*32;
  const bool isg = (wv == 0) && hi;    // tanh row

  __shared__ __align__(16) float hbuf[2][HL];     // per-wave private h
  __shared__ __align__(16) float pre[2][128];     // ping-pong gate activations
  __shared__ unsigned long long azm[2];

  unsigned long long bz = __ballot(pb == 0.0f);
  if (lane == 0) azm[wv] = bz;
  if (!hi) hbuf[wv][sub] = 0.0f;
  WBAR();
  bool allzero = (azm[0] == ~0ull) && (azm[1] == ~0ull);

  int t0, dt;
  bool skipall = false;
  if (dir == 0){ t0 = 0; dt = 1; }
  else if (allzero){
    // zero bias + zero input keeps state exactly 0 -> rows >= cnt are 0
    for (int rr = cnt + (wv*2 + hi); rr < TS; rr += 4) outg[(size_t)rr*64 + sub] = 0.0f;
    t0 = cnt - 1; dt = -1;
    if (t0 < 0) skipall = true;
  } else { t0 = TS - 1; dt = -1; }

  float c = 0.0f, h = 0.0f;
  bool fwdconv = false;
  float4 X[4];
  int t = t0, ph = 0;

  if (!skipall){
    if (cnt > 0){
      int ta = t0 < 0 ? 0 : (t0 > cnt-1 ? cnt-1 : t0);
      const float* pa = h2in + (size_t)(s0 + ta)*HG;
#pragma unroll
      for (int q = 0; q < 4; q++) X[q] = uload4(pa + 4*q);
    }
    for (;;){
      float a0 = pb, a1 = 0.0f, a2 = 0.0f, a3 = 0.0f;
      if (t < cnt){
#pragma unroll
        for (int q = 0; q < 4; q++){ float4 xq = X[q];
          a0 = fmaf(xq.x, wx[4*q+0], a0); a1 = fmaf(xq.y, wx[4*q+1], a1);
          a2 = fmaf(xq.z, wx[4*q+2], a2); a3 = fmaf(xq.w, wx[4*q+3], a3); }
      }
      // prefetch next row (vmcnt; survives the raw barrier)
      if (cnt > 0){
        int tp = t + dt; tp = tp < 0 ? 0 : (tp > cnt-1 ? cnt-1 : tp);
        const float* pp = h2in + (size_t)(s0 + tp)*HG;
#pragma unroll
        for (int q = 0; q < 4; q++) X[q] = uload4(pp + 4*q);
      }
      { const float4* h4 = (const float4*)hbuf[wv];
#pragma unroll
        for (int q = 0; q < HL/4; q++){ float4 hq = h4[q];
          a0 = fmaf(hq.x, wh[4*q+0], a0); a1 = fmaf(hq.y, wh[4*q+1], a1);
          a2 = fmaf(hq.z, wh[4*q+2], a2); a3 = fmaf(hq.w, wh[4*q+3], a3); }
      }
      float a = (a0 + a1) + (a2 + a3);
      float u = isg ? (a + a) : a;
      float sv = sigf(u);
      float val = isg ? (sv + sv - 1.0f) : sv;   // i/f/o: sig, g: tanh
      pre[ph][wv*64 + lane] = val;
      WBAR();
      float vi, vg, vf, vo;
      if (wv == 0){
        vi = __shfl(val, sub); vg = __shfl(val, 32 + sub);
        vf = pre[ph][64 + sub]; vo = pre[ph][96 + sub];
      } else {
        vf = __shfl(val, sub); vo = __shfl(val, 32 + sub);
        vi = pre[ph][sub];      vg = pre[ph][32 + sub];
      }
      float cn = fmaf(vf, c, vi * vg);
      float hn = vo * tanhfast(cn);
      bool eq = (fabsf(cn - c) <= CEPS*(1.0f + fabsf(cn))) && (fabsf(hn - h) <= HEPS);
      c = cn; h = hn;
      unsigned long long m = __ballot(eq);
      if (!hi) hbuf[wv][sub] = h;
      if (wv == 1 && hi) outg[(size_t)t*64 + sub] = h;
      if (dir == 0 && t >= cnt + 1 && m == ~0ull){
        // state (approx) fixed under constant zero input: tail rows = h*
        for (int rr = t + 1 + (wv*2 + hi); rr < TS; rr += 4) outg[(size_t)rr*64 + sub] = h;
        if (tid == 0) tconv[g] = t - 1;
        fwdconv = true;
        break;
      }
      t += dt;
      if (dir == 0){ if (t >= TS) break; } else { if (t < 0) break; }
      ph ^= 1;
    }
  }
  if (dir == 0 && !fwdconv && tid == 0) tconv[g] = TS;
}

// ---------------- layer 1 + mean pool ----------------
__global__ __launch_bounds__(128, 2) void k_lstm1(
    const float* __restrict__ gl0, const int* __restrict__ tconv,
    const float* __restrict__ wih, const float* __restrict__ whh,
    const float* __restrict__ bih, const float* __restrict__ bhh,
    float* __restrict__ pooled)
{
  const int g = blockIdx.x >> 1, dir = blockIdx.x & 1;
  const int tid = threadIdx.x;
  const int wv = tid >> 6, lane = tid & 63;
  const int sub = lane & 31, hi = lane >> 5;
  const int r = (hi ? 64 : 0) + (wv ? 32 : 0) + sub;
  float wx[64], wh[HL];
  { const float* wp = wih + (size_t)dir*128*64 + (size_t)r*64;
    const float* up = whh + (size_t)dir*128*HL + (size_t)r*HL;
#pragma unroll
    for (int k = 0; k < 64; k++) wx[k] = wp[k];
#pragma unroll
    for (int k = 0; k < HL; k++) wh[k] = up[k];
  }
  const float pb = bih[dir*128 + r] + bhh[dir*128 + r];
  const float* gin = gl0 + (size_t)g*TS*64;
  const int tcv = tconv[g];
  const bool isg = (wv == 0) && hi;

  __shared__ __align__(16) float hbuf[2][HL];
  __shared__ __align__(16) float pre[2][128];

  if (!hi) hbuf[wv][sub] = 0.0f;
  WBAR();

  const int t0 = dir ? (TS - 1) : 0, dt = dir ? -1 : 1;
  float c = 0.0f, h = 0.0f, hsum = 0.0f;
  float4 X[16];
  int t = t0, ph = 0;
  { const float* pa = gin + (size_t)t0*64;
#pragma unroll
    for (int q = 0; q < 16; q++) X[q] = uload4(pa + 4*q);
  }

  for (;;){
    float a0 = pb, a1 = 0.0f, a2 = 0.0f, a3 = 0.0f;
#pragma unroll
    for (int q = 0; q < 16; q++){ float4 xq = X[q];
      a0 = fmaf(xq.x, wx[4*q+0], a0); a1 = fmaf(xq.y, wx[4*q+1], a1);
      a2 = fmaf(xq.z, wx[4*q+2], a2); a3 = fmaf(xq.w, wx[4*q+3], a3); }
    { int tp = t + dt; tp = tp < 0 ? 0 : (tp > TS-1 ? TS-1 : tp);
      const float* pp = gin + (size_t)tp*64;
#pragma unroll
      for (int q = 0; q < 16; q++) X[q] = uload4(pp + 4*q);
    }
    { const float4* h4 = (const float4*)hbuf[wv];
#pragma unroll
      for (int q = 0; q < HL/4; q++){ float4 hq = h4[q];
        a0 = fmaf(hq.x, wh[4*q+0], a0); a1 = fmaf(hq.y, wh[4*q+1], a1);
        a2 = fmaf(hq.z, wh[4*q+2], a2); a3 = fmaf(hq.w, wh[4*q+3], a3); }
    }
    float a = (a0 + a1) + (a2 + a3);
    float u = isg ? (a + a) : a;
    float sv = sigf(u);
    float val = isg ? (sv + sv - 1.0f) : sv;
    pre[ph][wv*64 + lane] = val;
    WBAR();
    float vi, vg, vf, vo;
    if (wv == 0){
      vi = __shfl(val, sub); vg = __shfl(val, 32 + sub);
      vf = pre[ph][64 + sub]; vo = pre[ph][96 + sub];
    } else {
      vf = __shfl(val, sub); vo = __shfl(val, 32 + sub);
      vi = pre[ph][sub];      vg = pre[ph][32 + sub];
    }
    float cn = fmaf(vf, c, vi * vg);
    float hn = vo * tanhfast(cn);
    bool eq = (fabsf(cn - c) <= CEPS*(1.0f + fabsf(cn))) && (fabsf(hn - h) <= HEPS);
    c = cn; h = hn;
    hsum += h;
    unsigned long long m = __ballot(eq);
    if (!hi) hbuf[wv][sub] = h;
    if (t >= tcv + 1 && m == ~0ull){
      if (dir == 0){
        // input const for all remaining t, state fixed -> close the mean
        hsum += h * (float)(TS - 1 - t);
        break;
      } else {
        // rows [tcv, t-1] equal current input; state fixed -> h* repeats
        hsum += h * (float)(t - tcv);
        t = tcv - 1;
        if (t < 0) break;
        const float* pa2 = gin + (size_t)t*64;
#pragma unroll
        for (int q = 0; q < 16; q++) X[q] = uload4(pa2 + 4*q);
        ph ^= 1;
        continue;
      }
    }
    t += dt;
    if (dir == 0){ if (t >= TS) break; } else { if (t < 0) break; }
    ph ^= 1;
  }
  if (wv == 0 && !hi) pooled[(size_t)g*64 + dir*32 + sub] = hsum * (1.0f/(float)TS);
}

// ---------------- FC: out = pooled @ fc_w + fc_b ----------------
__global__ void k_fc(const float* __restrict__ pooled, const float* __restrict__ fcw,
                     const float* __restrict__ fcb, float* __restrict__ out){
  __shared__ float p[64];
  int g = blockIdx.x, cix = threadIdx.x;
  if (cix < 64) p[cix] = pooled[(size_t)g*64 + cix];
  __syncthreads();
  float acc = fcb[cix];
#pragma unroll
  for (int k = 0; k < 64; k++) acc = fmaf(p[k], fcw[k*NC + cix], acc);
  out[(size_t)g*NC + cix] = acc;
}

extern "C" void kernel_launch(void* const* d_in, const int* in_sizes, int n_in,
                              void* d_out, int out_size, void* d_ws, size_t ws_size,
                              hipStream_t stream) {
  const float* x        = (const float*)d_in[0];
  const int*   ei       = (const int*)  d_in[1];
  const int*   batch    = (const int*)  d_in[2];
  const float* gcn_w1   = (const float*)d_in[3];
  const float* gcn_b1   = (const float*)d_in[4];
  const float* gcn_w2   = (const float*)d_in[5];
  const float* gcn_b2   = (const float*)d_in[6];
  const float* l0_wih   = (const float*)d_in[7];
  const float* l0_whh   = (const float*)d_in[8];
  const float* l0_bih   = (const float*)d_in[9];
  const float* l0_bhh   = (const float*)d_in[10];
  const float* l1_wih   = (const float*)d_in[11];
  const float* l1_whh   = (const float*)d_in[12];
  const float* l1_bih   = (const float*)d_in[13];
  const float* l1_bhh   = (const float*)d_in[14];
  const float* fc_w     = (const float*)d_in[15];
  const float* fc_b     = (const float*)d_in[16];
  float* out = (float*)d_out;

  // workspace layout (4B units)
  float* ws   = (float*)d_ws;
  float* B0   = ws;                        // NN*16
  float* B1   = B0 + (size_t)NN*HG;        // NN*16
  float* B2   = B1 + (size_t)NN*HG;        // NN*16
  float* dinv = B2 + (size_t)NN*HG;        // NN
  int*   ecnt   = (int*)(dinv + NN);       // NN
  int*   eoff   = ecnt + NN;               // NN
  int*   cursor = eoff + NN;               // NN
  int*   counts = cursor + NN;             // 512
  int*   starts = counts + NG;             // 512
  int*   tconv  = starts + NG;             // 512
  int*   bsum   = tconv + NG;              // 512
  int*   bstart = bsum + NG;               // 512
  float* pooled = (float*)(bstart + NG);   // 512*64
  int*   csr    = (int*)(pooled + (size_t)NG*64);  // NE
  float* out0   = (float*)(csr + (size_t)NE);      // 512*1024*64
  size_t needed = ((size_t)((float*)out0 - ws) + (size_t)NG*TS*64) * sizeof(float);
  if (ws_size < needed) return;  // fail loudly (poisoned d_out) rather than corrupt

  k_init0 <<<(NN+255)/256, 256, 0, stream>>>(ecnt, counts);
  k_count <<<(NE+255)/256, 256, 0, stream>>>(ei, batch, ecnt, counts);
  k_bsum  <<<NN/256, 256, 0, stream>>>(ecnt, bsum);
  k_scan2 <<<1, NG, 0, stream>>>(counts, starts, bsum, bstart);
  k_eoff  <<<NN/256, 256, 0, stream>>>(ecnt, bstart, eoff, cursor);
  k_dinv  <<<(NN+255)/256, 256, 0, stream>>>(ecnt, dinv);
  k_place <<<(NE+255)/256, 256, 0, stream>>>(ei, cursor, csr);
  k_lin1  <<<NN/16, 256, 0, stream>>>(x, gcn_w1, B0);
  k_gather<<<(NN*HG)/256, 256, 0, stream>>>(B0, csr, eoff, ecnt, dinv, gcn_b2, 0, B1);
  k_relu_lin<<<(NN*HG)/256, 256, 0, stream>>>(B1, gcn_b1, gcn_w2, B2);
  k_gather<<<(NN*HG)/256, 256, 0, stream>>>(B2, csr, eoff, ecnt, dinv, gcn_b2, 1, B1);
  k_lstm0 <<<NG*2, 128, 0, stream>>>(B1, starts, counts, l0_wih, l0_whh, l0_bih, l0_bhh, out0, tconv);
  k_lstm1 <<<NG*2, 128, 0, stream>>>(out0, tconv, l1_wih, l1_whh, l1_bih, l1_bhh, pooled);
  k_fc    <<<NG, NC, 0, stream>>>(pooled, fc_w, fc_b, out);
}

// Round 9
// 1158.809 us; speedup vs baseline: 1.6593x; 1.2527x over previous
//
#include <hip/hip_runtime.h>
#include <cstdint>
#include <cstddef>

#define NG 512        // NUM_GRAPHS
#define NN 131072     // N_NODES
#define NE 4194304    // N_EDGES
#define FIN 54        // F_IN
#define HG 16         // H_GCN
#define HL 32         // H_LSTM
#define NC 192        // N_CLASSES
#define TS 1024       // MAX_SEQ_LEN

#define NB 256        // dst buckets (dst>>9), 512 nodes each
#define WH 512        // histogram/scatter workgroups, 8192 edges each
#define EPW (NE/WH)   // 8192

__device__ __forceinline__ float rcpf(float x){ return __builtin_amdgcn_rcpf(x); }
__device__ __forceinline__ float sigf(float x){ return rcpf(1.0f + __expf(-x)); }
__device__ __forceinline__ float tanhfast(float x){ return 1.0f - 2.0f*rcpf(__expf(2.0f*x) + 1.0f); }

// Wave-uniform row load kept in the VECTOR (vmcnt) domain (R5 lesson: s_load
// shares lgkmcnt with DS, out-of-order -> serializing waits).
__device__ __forceinline__ float4 uload4(const float* p){
  unsigned long long a = (unsigned long long)p;
  asm volatile("" : "+v"(a));
  return *(const float4*)a;
}

// Raw barrier: drain LDS only (lgkmcnt), NOT vmcnt — keeps x prefetch in flight.
#define WBAR() asm volatile("s_waitcnt lgkmcnt(0)\ns_barrier" ::: "memory")

#define CEPS 1e-6f
#define HEPS 1e-6f

// ---------------- counts = 0 ----------------
__global__ void k_initc(int* __restrict__ counts){
  counts[threadIdx.x] = 0;
}

// ---------------- per-graph node counts ----------------
__global__ void k_cnt(const int* __restrict__ batch, int* __restrict__ counts){
  int i = blockIdx.x*256 + threadIdx.x;
  if (i < NN) atomicAdd(&counts[batch[i]], 1);
}

// ---------------- exclusive scan of counts -> starts (1 block, 512 thr) ----------------
__global__ void k_scan(const int* __restrict__ counts, int* __restrict__ starts){
  __shared__ int sc[NG];
  int t = threadIdx.x;
  sc[t] = counts[t]; __syncthreads();
  for (int off = 1; off < NG; off <<= 1){
    int v = (t >= off) ? sc[t-off] : 0;
    __syncthreads();
    sc[t] += v;
    __syncthreads();
  }
  starts[t] = sc[t] - counts[t];
}

// ---------------- bucket histogram: hist[b*WH + w] ----------------
__global__ void k_hist(const int* __restrict__ ei, int* __restrict__ hist){
  int w = blockIdx.x, tid = threadIdx.x;
  __shared__ int h[NB];
  h[tid] = 0;
  __syncthreads();
  int e0 = w*EPW;
  for (int i = tid; i < EPW; i += 256) atomicAdd(&h[ei[NE + e0 + i] >> 9], 1);
  __syncthreads();
  hist[tid*WH + w] = h[tid];
}

// ---------------- scan 131072-entry histogram (1 block, 1024 thr) ----------------
__global__ void k_scanH(const int* __restrict__ hist, int* __restrict__ offs,
                        int* __restrict__ bstart){
  __shared__ int tot[1024];
  int t = threadIdx.x;
  int base = t*128;
  int s = 0;
  for (int i = 0; i < 128; i++) s += hist[base + i];
  tot[t] = s; __syncthreads();
  for (int o = 1; o < 1024; o <<= 1){
    int v = (t >= o) ? tot[t-o] : 0;
    __syncthreads();
    tot[t] += v;
    __syncthreads();
  }
  int run = tot[t] - s;
  for (int i = 0; i < 128; i++){
    int idx = base + i;
    int h = hist[idx];
    offs[idx] = run;
    if ((idx & (WH-1)) == 0) bstart[idx / WH] = run;
    run += h;
  }
  if (t == 0) bstart[NB] = NE;
}

// ---------------- bin pass B: scatter (src, dst&511) into bucket-sorted pairs ----------------
// Writes are contiguous per (bucket, wg) run -> sequential bursts, no 64B split.
__global__ void k_binB(const int* __restrict__ ei, const int* __restrict__ offs,
                       uint2* __restrict__ pair){
  int w = blockIdx.x, tid = threadIdx.x;
  __shared__ int cur[NB];
  cur[tid] = offs[tid*WH + w];
  __syncthreads();
  int e0 = w*EPW;
  for (int i = tid; i < EPW; i += 256){
    int e = e0 + i;
    int s = ei[e], d = ei[NE + e];
    int b = d >> 9;
    int pos = atomicAdd(&cur[b], 1);
    pair[pos] = make_uint2((unsigned)s, (unsigned)(d & 511));
  }
}

// ---------------- bin pass C: per-bucket CSR finalize (one wg per bucket) ----------------
// Emits eoff/ecnt from the local histogram (replaces global ecnt atomics +
// bsum + eoff kernels). csr writes span only this bucket's ~65KB range -> L2-merged.
__global__ void k_binC(const uint2* __restrict__ pair, const int* __restrict__ bstart,
                       int* __restrict__ eoff, int* __restrict__ ecnt, int* __restrict__ csr){
  int b = blockIdx.x, tid = threadIdx.x;
  __shared__ int h2[512];
  __shared__ int cur[512];
  h2[tid] = 0; h2[tid + 256] = 0;
  __syncthreads();
  int e0 = bstart[b], e1 = bstart[b+1];
  for (int i = e0 + tid; i < e1; i += 256) atomicAdd(&h2[pair[i].y], 1);
  __syncthreads();
  // inclusive scan of 512 via two halves of 256
  cur[tid] = h2[tid]; cur[tid + 256] = h2[tid + 256];
  __syncthreads();
  for (int o = 1; o < 256; o <<= 1){
    int v0 = (tid >= o) ? cur[tid - o] : 0;
    int v1 = (tid >= o) ? cur[256 + tid - o] : 0;
    __syncthreads();
    cur[tid] += v0; cur[256 + tid] += v1;
    __syncthreads();
  }
  int half0 = cur[255];
  __syncthreads();
  cur[256 + tid] += half0;
  __syncthreads();
  int n0 = tid, n1 = tid + 256;
  int ex0 = cur[n0] - h2[n0];
  int ex1 = cur[n1] - h2[n1];
  eoff[b*512 + n0] = e0 + ex0; ecnt[b*512 + n0] = h2[n0];
  eoff[b*512 + n1] = e0 + ex1; ecnt[b*512 + n1] = h2[n1];
  __syncthreads();
  cur[n0] = e0 + ex0; cur[n1] = e0 + ex1;
  __syncthreads();
  for (int i = e0 + tid; i < e1; i += 256){
    uint2 u = pair[i];
    int pos = atomicAdd(&cur[u.y], 1);
    csr[pos] = (int)u.x;
  }
}

__global__ void k_dinv(const int* __restrict__ ecnt, float* __restrict__ dinv){
  int i = blockIdx.x*256 + threadIdx.x;
  if (i < NN) dinv[i] = 1.0f / sqrtf((float)(ecnt[i] + 1));  // deg = indeg + self-loop >= 1
}

// ---------------- xa = x @ w1 : stage x rows via LDS ----------------
__global__ void k_lin1(const float* __restrict__ x, const float* __restrict__ w1,
                       float* __restrict__ xa){
  __shared__ float w[FIN*HG];       // 864
  __shared__ float xs[16][FIN+2];   // pad to 56
  int tid = threadIdx.x;
  for (int i = tid; i < FIN*HG; i += 256) w[i] = w1[i];
  const float4* gx = (const float4*)(x + (size_t)blockIdx.x*16*FIN);
  if (tid < 216){
    float4 v4 = gx[tid];
    int fi = tid*4;
#pragma unroll
    for (int e = 0; e < 4; e++){
      int idx = fi + e;
      xs[idx/FIN][idx%FIN] = ((const float*)&v4)[e];
    }
  }
  __syncthreads();
  int node = tid >> 4, f = tid & 15;
  const float* xr = xs[node];
  float acc = 0.0f;
#pragma unroll
  for (int k = 0; k < FIN; k++) acc = fmaf(xr[k], w[k*HG + f], acc);
  xa[((size_t)blockIdx.x*16 + node)*HG + f] = acc;
}

// ---------------- gather conv (no atomics): 16 lanes per dst node ----------------
__global__ void k_gather(const float* __restrict__ v, const int* __restrict__ csr,
                         const int* __restrict__ eoff, const int* __restrict__ ecnt,
                         const float* __restrict__ dinv, const float* __restrict__ bias,
                         int dorelu, float* __restrict__ out){
  int gid = blockIdx.x*16 + (threadIdx.x >> 4);
  int f = threadIdx.x & 15;
  float dv = dinv[gid];
  float a0 = v[(size_t)gid*HG + f] * dv, a1 = 0.0f, a2 = 0.0f, a3 = 0.0f;
  int o = eoff[gid], n = ecnt[gid];
  int i = 0;
  for (; i + 8 <= n; i += 8){
    int s0 = csr[o+i],   s1 = csr[o+i+1], s2 = csr[o+i+2], s3 = csr[o+i+3];
    int s4 = csr[o+i+4], s5 = csr[o+i+5], s6 = csr[o+i+6], s7 = csr[o+i+7];
    a0 = fmaf(v[(size_t)s0*HG + f], dinv[s0], a0);
    a1 = fmaf(v[(size_t)s1*HG + f], dinv[s1], a1);
    a2 = fmaf(v[(size_t)s2*HG + f], dinv[s2], a2);
    a3 = fmaf(v[(size_t)s3*HG + f], dinv[s3], a3);
    a0 = fmaf(v[(size_t)s4*HG + f], dinv[s4], a0);
    a1 = fmaf(v[(size_t)s5*HG + f], dinv[s5], a1);
    a2 = fmaf(v[(size_t)s6*HG + f], dinv[s6], a2);
    a3 = fmaf(v[(size_t)s7*HG + f], dinv[s7], a3);
  }
  for (; i + 4 <= n; i += 4){
    int s0 = csr[o+i], s1 = csr[o+i+1], s2 = csr[o+i+2], s3 = csr[o+i+3];
    a0 = fmaf(v[(size_t)s0*HG + f], dinv[s0], a0);
    a1 = fmaf(v[(size_t)s1*HG + f], dinv[s1], a1);
    a2 = fmaf(v[(size_t)s2*HG + f], dinv[s2], a2);
    a3 = fmaf(v[(size_t)s3*HG + f], dinv[s3], a3);
  }
  for (; i < n; i++){
    int s = csr[o+i];
    a0 = fmaf(v[(size_t)s*HG + f], dinv[s], a0);
  }
  float acc = ((a0 + a1) + (a2 + a3)) * dv;
  if (dorelu) acc = fmaxf(acc + bias[f], 0.0f);
  out[(size_t)gid*HG + f] = acc;
}

// ---------------- hb = relu(agg + b1) @ w2 ----------------
__global__ void k_relu_lin(const float* __restrict__ agg, const float* __restrict__ b1,
                           const float* __restrict__ w2, float* __restrict__ hb){
  __shared__ float w[HG*HG];
  __shared__ float bb[HG];
  int tid = threadIdx.x;
  if (tid < HG*HG) w[tid] = w2[tid];
  if (tid < HG) bb[tid] = b1[tid];
  __syncthreads();
  int id = blockIdx.x*256 + tid;
  if (id >= NN*HG) return;
  int node = id >> 4, f = id & 15;
  const float* ar = agg + (size_t)node*HG;
  float acc = 0.0f;
#pragma unroll
  for (int k = 0; k < HG; k++){
    float h = fmaxf(ar[k] + bb[k], 0.0f);
    acc = fmaf(h, w[k*HG + f], acc);
  }
  hb[id] = acc;
}

// ============ BiLSTM: 2 waves/chain, 1 barrier/step, redundant c,h ============
// Row map: wave0 lo = i_sub, wave0 hi = g_sub, wave1 lo = f_sub, wave1 hi = o_sub.
// Per step: each wave computes its 64 gate ACTIVATIONS -> ping-pong LDS; ONE
// WBAR; both waves gather (2 shfl own + 2 LDS foreign) and compute c,h
// REDUNDANTLY (bitwise identical -> wave-local convergence ballot, no flag).
// h lives in per-wave private LDS (within-wave DS order -> no barrier).
// x rows per-lane in registers via uload4 (vmcnt domain, prefetch 1 ahead).

// ---------------- layer 0 ----------------
__global__ __launch_bounds__(128, 2) void k_lstm0(
    const float* __restrict__ h2in, const int* __restrict__ starts, const int* __restrict__ counts,
    const float* __restrict__ wih, const float* __restrict__ whh,
    const float* __restrict__ bih, const float* __restrict__ bhh,
    float* __restrict__ out0, int* __restrict__ tconv)
{
  const int g = blockIdx.x >> 1, dir = blockIdx.x & 1;
  const int tid = threadIdx.x;
  const int wv = tid >> 6, lane = tid & 63;
  const int sub = lane & 31, hi = lane >> 5;
  const int r = (hi ? 64 : 0) + (wv ? 32 : 0) + sub;   // i/g/f/o row
  float wx[HG], wh[HL];
  { const float* wp = wih + (size_t)dir*128*HG + (size_t)r*HG;
    const float* up = whh + (size_t)dir*128*HL + (size_t)r*HL;
#pragma unroll
    for (int k = 0; k < HG; k++) wx[k] = wp[k];
#pragma unroll
    for (int k = 0; k < HL; k++) wh[k] = up[k];
  }
  const float pb = bih[dir*128 + r] + bhh[dir*128 + r];
  int cnt = counts[g]; if (cnt > TS) cnt = TS;
  const int s0 = starts[g];
  float* outg = out0 + (size_t)g*TS*64 + dir*32;
  const bool isg = (wv == 0) && hi;    // tanh row

  __shared__ __align__(16) float hbuf[2][HL];     // per-wave private h
  __shared__ __align__(16) float pre[2][128];     // ping-pong gate activations
  __shared__ unsigned long long azm[2];

  unsigned long long bz = __ballot(pb == 0.0f);
  if (lane == 0) azm[wv] = bz;
  if (!hi) hbuf[wv][sub] = 0.0f;
  WBAR();
  bool allzero = (azm[0] == ~0ull) && (azm[1] == ~0ull);

  int t0, dt;
  bool skipall = false;
  if (dir == 0){ t0 = 0; dt = 1; }
  else if (allzero){
    // zero bias + zero input keeps state exactly 0 -> rows >= cnt are 0
    for (int rr = cnt + (wv*2 + hi); rr < TS; rr += 4) outg[(size_t)rr*64 + sub] = 0.0f;
    t0 = cnt - 1; dt = -1;
    if (t0 < 0) skipall = true;
  } else { t0 = TS - 1; dt = -1; }

  float c = 0.0f, h = 0.0f;
  bool fwdconv = false;
  float4 X[4];
  int t = t0, ph = 0;

  if (!skipall){
    if (cnt > 0){
      int ta = t0 < 0 ? 0 : (t0 > cnt-1 ? cnt-1 : t0);
      const float* pa = h2in + (size_t)(s0 + ta)*HG;
#pragma unroll
      for (int q = 0; q < 4; q++) X[q] = uload4(pa + 4*q);
    }
    for (;;){
      float a0 = pb, a1 = 0.0f, a2 = 0.0f, a3 = 0.0f;
      if (t < cnt){
#pragma unroll
        for (int q = 0; q < 4; q++){ float4 xq = X[q];
          a0 = fmaf(xq.x, wx[4*q+0], a0); a1 = fmaf(xq.y, wx[4*q+1], a1);
          a2 = fmaf(xq.z, wx[4*q+2], a2); a3 = fmaf(xq.w, wx[4*q+3], a3); }
      }
      // prefetch next row (vmcnt; survives the raw barrier)
      if (cnt > 0){
        int tp = t + dt; tp = tp < 0 ? 0 : (tp > cnt-1 ? cnt-1 : tp);
        const float* pp = h2in + (size_t)(s0 + tp)*HG;
#pragma unroll
        for (int q = 0; q < 4; q++) X[q] = uload4(pp + 4*q);
      }
      { const float4* h4 = (const float4*)hbuf[wv];
#pragma unroll
        for (int q = 0; q < HL/4; q++){ float4 hq = h4[q];
          a0 = fmaf(hq.x, wh[4*q+0], a0); a1 = fmaf(hq.y, wh[4*q+1], a1);
          a2 = fmaf(hq.z, wh[4*q+2], a2); a3 = fmaf(hq.w, wh[4*q+3], a3); }
      }
      float a = (a0 + a1) + (a2 + a3);
      float u = isg ? (a + a) : a;
      float sv = sigf(u);
      float val = isg ? (sv + sv - 1.0f) : sv;   // i/f/o: sig, g: tanh
      pre[ph][wv*64 + lane] = val;
      WBAR();
      float vi, vg, vf, vo;
      if (wv == 0){
        vi = __shfl(val, sub); vg = __shfl(val, 32 + sub);
        vf = pre[ph][64 + sub]; vo = pre[ph][96 + sub];
      } else {
        vf = __shfl(val, sub); vo = __shfl(val, 32 + sub);
        vi = pre[ph][sub];      vg = pre[ph][32 + sub];
      }
      float cn = fmaf(vf, c, vi * vg);
      float hn = vo * tanhfast(cn);
      bool eq = (fabsf(cn - c) <= CEPS*(1.0f + fabsf(cn))) && (fabsf(hn - h) <= HEPS);
      c = cn; h = hn;
      unsigned long long m = __ballot(eq);
      if (!hi) hbuf[wv][sub] = h;
      if (wv == 1 && hi) outg[(size_t)t*64 + sub] = h;
      if (dir == 0 && t >= cnt + 1 && m == ~0ull){
        // state (approx) fixed under constant zero input: tail rows = h*
        for (int rr = t + 1 + (wv*2 + hi); rr < TS; rr += 4) outg[(size_t)rr*64 + sub] = h;
        if (tid == 0) tconv[g] = t - 1;
        fwdconv = true;
        break;
      }
      t += dt;
      if (dir == 0){ if (t >= TS) break; } else { if (t < 0) break; }
      ph ^= 1;
    }
  }
  if (dir == 0 && !fwdconv && tid == 0) tconv[g] = TS;
}

// ---------------- layer 1 + mean pool ----------------
__global__ __launch_bounds__(128, 2) void k_lstm1(
    const float* __restrict__ gl0, const int* __restrict__ tconv,
    const float* __restrict__ wih, const float* __restrict__ whh,
    const float* __restrict__ bih, const float* __restrict__ bhh,
    float* __restrict__ pooled)
{
  const int g = blockIdx.x >> 1, dir = blockIdx.x & 1;
  const int tid = threadIdx.x;
  const int wv = tid >> 6, lane = tid & 63;
  const int sub = lane & 31, hi = lane >> 5;
  const int r = (hi ? 64 : 0) + (wv ? 32 : 0) + sub;
  float wx[64], wh[HL];
  { const float* wp = wih + (size_t)dir*128*64 + (size_t)r*64;
    const float* up = whh + (size_t)dir*128*HL + (size_t)r*HL;
#pragma unroll
    for (int k = 0; k < 64; k++) wx[k] = wp[k];
#pragma unroll
    for (int k = 0; k < HL; k++) wh[k] = up[k];
  }
  const float pb = bih[dir*128 + r] + bhh[dir*128 + r];
  const float* gin = gl0 + (size_t)g*TS*64;
  const int tcv = tconv[g];
  const bool isg = (wv == 0) && hi;

  __shared__ __align__(16) float hbuf[2][HL];
  __shared__ __align__(16) float pre[2][128];

  if (!hi) hbuf[wv][sub] = 0.0f;
  WBAR();

  const int t0 = dir ? (TS - 1) : 0, dt = dir ? -1 : 1;
  float c = 0.0f, h = 0.0f, hsum = 0.0f;
  float4 X[16];
  int t = t0, ph = 0;
  { const float* pa = gin + (size_t)t0*64;
#pragma unroll
    for (int q = 0; q < 16; q++) X[q] = uload4(pa + 4*q);
  }

  for (;;){
    float a0 = pb, a1 = 0.0f, a2 = 0.0f, a3 = 0.0f;
#pragma unroll
    for (int q = 0; q < 16; q++){ float4 xq = X[q];
      a0 = fmaf(xq.x, wx[4*q+0], a0); a1 = fmaf(xq.y, wx[4*q+1], a1);
      a2 = fmaf(xq.z, wx[4*q+2], a2); a3 = fmaf(xq.w, wx[4*q+3], a3); }
    { int tp = t + dt; tp = tp < 0 ? 0 : (tp > TS-1 ? TS-1 : tp);
      const float* pp = gin + (size_t)tp*64;
#pragma unroll
      for (int q = 0; q < 16; q++) X[q] = uload4(pp + 4*q);
    }
    { const float4* h4 = (const float4*)hbuf[wv];
#pragma unroll
      for (int q = 0; q < HL/4; q++){ float4 hq = h4[q];
        a0 = fmaf(hq.x, wh[4*q+0], a0); a1 = fmaf(hq.y, wh[4*q+1], a1);
        a2 = fmaf(hq.z, wh[4*q+2], a2); a3 = fmaf(hq.w, wh[4*q+3], a3); }
    }
    float a = (a0 + a1) + (a2 + a3);
    float u = isg ? (a + a) : a;
    float sv = sigf(u);
    float val = isg ? (sv + sv - 1.0f) : sv;
    pre[ph][wv*64 + lane] = val;
    WBAR();
    float vi, vg, vf, vo;
    if (wv == 0){
      vi = __shfl(val, sub); vg = __shfl(val, 32 + sub);
      vf = pre[ph][64 + sub]; vo = pre[ph][96 + sub];
    } else {
      vf = __shfl(val, sub); vo = __shfl(val, 32 + sub);
      vi = pre[ph][sub];      vg = pre[ph][32 + sub];
    }
    float cn = fmaf(vf, c, vi * vg);
    float hn = vo * tanhfast(cn);
    bool eq = (fabsf(cn - c) <= CEPS*(1.0f + fabsf(cn))) && (fabsf(hn - h) <= HEPS);
    c = cn; h = hn;
    hsum += h;
    unsigned long long m = __ballot(eq);
    if (!hi) hbuf[wv][sub] = h;
    if (t >= tcv + 1 && m == ~0ull){
      if (dir == 0){
        // input const for all remaining t, state fixed -> close the mean
        hsum += h * (float)(TS - 1 - t);
        break;
      } else {
        // rows [tcv, t-1] equal current input; state fixed -> h* repeats
        hsum += h * (float)(t - tcv);
        t = tcv - 1;
        if (t < 0) break;
        const float* pa2 = gin + (size_t)t*64;
#pragma unroll
        for (int q = 0; q < 16; q++) X[q] = uload4(pa2 + 4*q);
        ph ^= 1;
        continue;
      }
    }
    t += dt;
    if (dir == 0){ if (t >= TS) break; } else { if (t < 0) break; }
    ph ^= 1;
  }
  if (wv == 0 && !hi) pooled[(size_t)g*64 + dir*32 + sub] = hsum * (1.0f/(float)TS);
}

// ---------------- FC: out = pooled @ fc_w + fc_b ----------------
__global__ void k_fc(const float* __restrict__ pooled, const float* __restrict__ fcw,
                     const float* __restrict__ fcb, float* __restrict__ out){
  __shared__ float p[64];
  int g = blockIdx.x, cix = threadIdx.x;
  if (cix < 64) p[cix] = pooled[(size_t)g*64 + cix];
  __syncthreads();
  float acc = fcb[cix];
#pragma unroll
  for (int k = 0; k < 64; k++) acc = fmaf(p[k], fcw[k*NC + cix], acc);
  out[(size_t)g*NC + cix] = acc;
}

extern "C" void kernel_launch(void* const* d_in, const int* in_sizes, int n_in,
                              void* d_out, int out_size, void* d_ws, size_t ws_size,
                              hipStream_t stream) {
  const float* x        = (const float*)d_in[0];
  const int*   ei       = (const int*)  d_in[1];
  const int*   batch    = (const int*)  d_in[2];
  const float* gcn_w1   = (const float*)d_in[3];
  const float* gcn_b1   = (const float*)d_in[4];
  const float* gcn_w2   = (const float*)d_in[5];
  const float* gcn_b2   = (const float*)d_in[6];
  const float* l0_wih   = (const float*)d_in[7];
  const float* l0_whh   = (const float*)d_in[8];
  const float* l0_bih   = (const float*)d_in[9];
  const float* l0_bhh   = (const float*)d_in[10];
  const float* l1_wih   = (const float*)d_in[11];
  const float* l1_whh   = (const float*)d_in[12];
  const float* l1_bih   = (const float*)d_in[13];
  const float* l1_bhh   = (const float*)d_in[14];
  const float* fc_w     = (const float*)d_in[15];
  const float* fc_b     = (const float*)d_in[16];
  float* out = (float*)d_out;

  // workspace layout (4B units)
  float* ws   = (float*)d_ws;
  float* B0   = ws;                        // NN*16
  float* B1   = B0 + (size_t)NN*HG;        // NN*16
  float* B2   = B1 + (size_t)NN*HG;        // NN*16
  float* dinv = B2 + (size_t)NN*HG;        // NN
  int*   ecnt   = (int*)(dinv + NN);       // NN
  int*   eoff   = ecnt + NN;               // NN
  int*   hist   = eoff + NN;               // NB*WH = 131072
  int*   offs   = hist + NB*WH;            // 131072
  int*   counts = offs + NB*WH;            // 512
  int*   starts = counts + NG;             // 512
  int*   tconv  = starts + NG;             // 512
  int*   bstart = tconv + NG;              // NB+1
  float* pooled = (float*)(bstart + NB + 64);      // 512*64 (64-int pad)
  int*   csr    = (int*)(pooled + (size_t)NG*64);  // NE
  float* out0   = (float*)(csr + (size_t)NE);      // 512*1024*64
  uint2* pair   = (uint2*)out0;                    // NE*2 ints, aliases out0 (dead before lstm0)
  size_t needed = ((size_t)((float*)out0 - ws) + (size_t)NG*TS*64) * sizeof(float);
  if (ws_size < needed) return;  // fail loudly (poisoned d_out) rather than corrupt

  k_initc <<<1, NG, 0, stream>>>(counts);
  k_cnt   <<<NN/256, 256, 0, stream>>>(batch, counts);
  k_hist  <<<WH, 256, 0, stream>>>(ei, hist);
  k_scanH <<<1, 1024, 0, stream>>>(hist, offs, bstart);
  k_scan  <<<1, NG, 0, stream>>>(counts, starts);
  k_binB  <<<WH, 256, 0, stream>>>(ei, offs, pair);
  k_binC  <<<NB, 256, 0, stream>>>(pair, bstart, eoff, ecnt, csr);
  k_dinv  <<<NN/256, 256, 0, stream>>>(ecnt, dinv);
  k_lin1  <<<NN/16, 256, 0, stream>>>(x, gcn_w1, B0);
  k_gather<<<(NN*HG)/256, 256, 0, stream>>>(B0, csr, eoff, ecnt, dinv, gcn_b2, 0, B1);
  k_relu_lin<<<(NN*HG)/256, 256, 0, stream>>>(B1, gcn_b1, gcn_w2, B2);
  k_gather<<<(NN*HG)/256, 256, 0, stream>>>(B2, csr, eoff, ecnt, dinv, gcn_b2, 1, B1);
  k_lstm0 <<<NG*2, 128, 0, stream>>>(B1, starts, counts, l0_wih, l0_whh, l0_bih, l0_bhh, out0, tconv);
  k_lstm1 <<<NG*2, 128, 0, stream>>>(out0, tconv, l1_wih, l1_whh, l1_bih, l1_bhh, pooled);
  k_fc    <<<NG, NC, 0, stream>>>(pooled, fc_w, fc_b, out);
}